// Round 4
// baseline (698.451 us; speedup 1.0000x reference)
//
#include <hip/hip_runtime.h>
#include <math.h>

typedef _Float16 f16;
typedef _Float16 f16x8 __attribute__((ext_vector_type(8)));
typedef float f32x4 __attribute__((ext_vector_type(4)));

// ---------------------------------------------------------------------------
// expand_sum_a: x[b,i] = sum_{s<Sin} src[s*plane + b*KIN + i]  (Sin=1: raw input)
// -> Aexp (rows x KIN*19 fp16)
// planes per row: [0,8K): basis-hi | [8K,16K): basis-lo | xh | xh | xl
// ---------------------------------------------------------------------------
__global__ __launch_bounds__(256) void expand_sum_a(
    const float* __restrict__ src, size_t plane, int Sin,
    f16* __restrict__ Aexp, int KIN, int shift)
{
    int idx = blockIdx.x * 256 + threadIdx.x;
    int i = idx & (KIN - 1);
    int b = idx >> shift;
    float x = 0.0f;
    for (int s = 0; s < Sin; ++s) x += src[(size_t)s * plane + idx];

    float xs = (x + 2.2f) * 2.5f;
    float fj = floorf(xs);
    int jj = (int)fj;
    float t = xs - fj;
    float t2 = t * t, t3 = t2 * t;
    float omt = 1.0f - t;
    float p0 = omt * omt * omt * (1.0f / 6.0f);
    float p1 = (3.0f * t3 - 6.0f * t2 + 4.0f) * (1.0f / 6.0f);
    float p2 = (-3.0f * t3 + 3.0f * t2 + 3.0f * t + 1.0f) * (1.0f / 6.0f);
    float p3 = t3 * (1.0f / 6.0f);

    union { f16 h[8]; uint4 v; } hi, lo;
    bool inr = (jj >= 0 && jj <= 10);
    #pragma unroll
    for (int cc = 0; cc < 8; ++cc) {
        int d = cc - (jj - 3);
        float v = 0.0f;
        if (inr) {
            if (d == 0) v = p0; else if (d == 1) v = p1;
            else if (d == 2) v = p2; else if (d == 3) v = p3;
        }
        f16 h = (f16)v;
        hi.h[cc] = h;
        lo.h[cc] = (f16)(v - (float)h);
    }
    size_t KEXP = (size_t)KIN * 19;
    f16* row = Aexp + (size_t)b * KEXP;
    *(uint4*)(row + (size_t)i * 8) = hi.v;
    *(uint4*)(row + (size_t)KIN * 8 + (size_t)i * 8) = lo.v;
    f16 xh = (f16)x;
    f16 xl = (f16)(x - (float)xh);
    int K16 = KIN * 16;
    row[K16 + i] = xh;
    row[K16 + KIN + i] = xh;
    row[K16 + 2 * KIN + i] = xl;
}

// ---------------------------------------------------------------------------
// prep_b (round-3 verified): planes [qw x8][qw x8][wh][wl][wh]
// pairing with A: (bh+bl)*qw + xh*wh + xh*wl + xl*wh
// ---------------------------------------------------------------------------
__global__ __launch_bounds__(256) void prep_b(
    const float* __restrict__ BW, const float* __restrict__ SW,
    f16* __restrict__ Bexp, int KIN, int shift)
{
    int idx = blockIdx.x * 256 + threadIdx.x;
    int i = idx & (KIN - 1);
    int o = idx >> shift;
    const float* sp = SW + ((size_t)o * KIN + i) * 8;
    union { f16 h[8]; uint4 v; } pk;
    #pragma unroll
    for (int cc = 0; cc < 8; ++cc)
        pk.h[cc] = (f16)(rintf(sp[cc] * 32.0f) * 0.03125f);  // n/32, exact in fp16
    size_t KEXP = (size_t)KIN * 19;
    f16* row = Bexp + (size_t)o * KEXP;
    *(uint4*)(row + (size_t)i * 8) = pk.v;
    *(uint4*)(row + (size_t)KIN * 8 + (size_t)i * 8) = pk.v;
    float w = BW[(size_t)o * KIN + i];
    f16 wh = (f16)w;
    f16 wl = (f16)(w - (float)wh);
    int K16 = KIN * 16;
    row[K16 + i] = wh;
    row[K16 + KIN + i] = wl;
    row[K16 + 2 * KIN + i] = wh;
}

// ---------------------------------------------------------------------------
// gemm_mfma R11: 256x256 block tile, 512 threads / 8 waves (2M x 4N), wave
// tile 128x64 (8x4 of 16x16x32 f16). 4-deep LDS ring of BK=32 K-tiles,
// prefetch distance 3. ONE barrier per K-tile placed BETWEEN reads and
// gloads (cross-barrier pipe overlap):
//   tile t: [12 ds_read_b128 (af,bf | ag)] -> vmcnt(4|0) -> s_barrier ->
//           [4 gload_lds(t+3)] -> lgkm(4) -> 16 MFMA -> lgkm(0) -> 16 MFMA
// R3 post-mortem: barrier AFTER MFMA drained both pipes at every tile edge
// (2305 cyc/tile vs floors matrix=1242 / LDS=1408). Now reads(t+1) issue
// right after own MFMA(t) -- concurrent with other waves' MFMA(t) -- and
// post-barrier MFMA starts on pre-issued reads.
// Sync ledger (audited):
//   fill: reads(t+1) pre-barrier(t+1) need slot (t+1)&3 = gloads issued at
//         t-2 (or prologue); vmcnt(4) before barrier(t) retires exactly
//         those (outstanding = 4 from t-2 + 4 from t-1; t's are post-barrier).
//         Ladder: rem>=2 -> 4, rem==1 -> 0, rem==0 -> no barrier. NT=1,2,3 ok.
//   overwrite: gloads(t) -> slot (t-1)&3; all waves' reads(t-1) are complete
//         (own lgkm(0) in iter t-1) before they reach barrier(t); gloads
//         issue post-barrier(t) -> no pending readers.
//   lgkm order: af,bf (8) | SB0 | ag (4); lgkm(4) = af+bf retired.
// XOR bank-swizzle (verified): LDS slot (row, kc16B) holds global
//   (row, kc ^ ((row>>1)&3)); staging linear-dest with per-lane global
//   kc_src = (lane&3)^((lane>>3)&3); read ko = ((lane>>4)^((lr>>1)&3))*8.
// XCD-bijective block swizzle: L = (b&7)*q + (b>>3) enumerated x-fastest.
// ---------------------------------------------------------------------------
__global__ __launch_bounds__(512, 2) void gemm_mfma(
    const f16* __restrict__ A, const f16* __restrict__ Bm,
    float* __restrict__ C, int Kfull, int Kc, size_t plane, int N)
{
    __shared__ __align__(16) f16 As[4][8192];   // [slot][256 rows x 32 k], 64B rows
    __shared__ __align__(16) f16 Bs[4][8192];   // [slot][256 rows x 32 k]

    const int tid = threadIdx.x;
    const int wave = tid >> 6, lane = tid & 63;

    // ---- XCD-aware bijective swizzle (nwg % 8 == 0 for all CH/S candidates) ----
    const int nwg = gridDim.x * gridDim.y * gridDim.z;
    const int b = blockIdx.x + gridDim.x * (blockIdx.y + gridDim.y * blockIdx.z);
    const int q = nwg >> 3;
    const int L = (b & 7) * q + (b >> 3);
    const int lx = L % gridDim.x;
    const int rest = L / gridDim.x;
    const int ly = rest % gridDim.y;
    const int lz = rest / gridDim.y;

    const int m0 = ly * 256, n0 = lx * 256;
    const int kb = lz * Kc;
    int kcl = Kfull - kb; if (kcl > Kc) kcl = Kc;
    const int NT = kcl >> 5;

    // staging: 32 chunks of 1KB per tile (A:0..15, B:16..31); wave owns 4.
    const int kc_src = (lane & 3) ^ ((lane >> 3) & 3);
    const f16* gb[4];
    int isA_[4], coff[4];
    #pragma unroll
    for (int j = 0; j < 4; ++j) {
        int cch = wave * 4 + j;
        int a = (cch < 16);
        int c8 = a ? cch : (cch - 16);
        int row0 = (a ? m0 : n0) + c8 * 16 + (lane >> 2);
        gb[j] = (a ? A : Bm) + (size_t)row0 * Kfull + kb + kc_src * 8;
        isA_[j] = a;
        coff[j] = c8 * 512;
    }

    f32x4 acc[8][4];
    #pragma unroll
    for (int i = 0; i < 8; ++i)
        #pragma unroll
        for (int j = 0; j < 4; ++j)
            acc[i][j] = (f32x4){0.f, 0.f, 0.f, 0.f};

    // prologue: tiles 0..2 into slots 0..2 (prefetch distance 3)
    #pragma unroll
    for (int s = 0; s < 3; ++s) {
        if (s < NT) {
            int k0 = s << 5;
            #pragma unroll
            for (int j = 0; j < 4; ++j) {
                f16* dp = isA_[j] ? &As[s][coff[j]] : &Bs[s][coff[j]];
                __builtin_amdgcn_global_load_lds(
                    (const __attribute__((address_space(1))) unsigned int*)(gb[j] + k0),
                    (__attribute__((address_space(3))) unsigned int*)dp, 16, 0, 0);
            }
        }
    }
    // slot 0 must be resident in every wave before first reads
    if (NT >= 3)      asm volatile("s_waitcnt vmcnt(8)" ::: "memory");
    else if (NT == 2) asm volatile("s_waitcnt vmcnt(4)" ::: "memory");
    else              asm volatile("s_waitcnt vmcnt(0)" ::: "memory");
    __builtin_amdgcn_s_barrier();
    asm volatile("" ::: "memory");

    const int lr = lane & 15;
    const int ko = (((lane >> 4) ^ ((lr >> 1) & 3)) & 3) * 8;   // swizzled k-offset (f16)
    const int wm = (wave & 1) * 128, wn = (wave >> 1) * 64;

    for (int t = 0; t < NT; ++t) {
        const int st = t & 3;
        const int ns = (t + 3) & 3;
        const bool pf = (t + 3 < NT);
        const int kn = (t + 3) << 5;
        const int rem = NT - 1 - t;

        // ---- top: 12 ds_reads issued (overlaps other waves' MFMA of t-1) ----
        f16x8 af[4], bf[4], ag[4];
        #pragma unroll
        for (int i = 0; i < 4; ++i)
            af[i] = *(const f16x8*)&As[st][(wm + i * 16 + lr) * 32 + ko];
        #pragma unroll
        for (int j = 0; j < 4; ++j)
            bf[j] = *(const f16x8*)&Bs[st][(wn + j * 16 + lr) * 32 + ko];
        __builtin_amdgcn_sched_barrier(0);   // keep af+bf as the first 8 ds ops
        #pragma unroll
        for (int i = 0; i < 4; ++i)
            ag[i] = *(const f16x8*)&As[st][(wm + 64 + i * 16 + lr) * 32 + ko];
        __builtin_amdgcn_sched_barrier(0);   // pin all 12 reads above barrier

        // retire gloads filling slot (t+1)&3 (issued at t-2 / prologue)
        if (rem >= 2)      asm volatile("s_waitcnt vmcnt(4)" ::: "memory");
        else if (rem == 1) asm volatile("s_waitcnt vmcnt(0)" ::: "memory");
        if (rem >= 1) {
            __builtin_amdgcn_s_barrier();
            asm volatile("" ::: "memory");
        }

        // ---- gloads for tile t+3 (slot ns has no pending readers now) ----
        if (pf) {
            #pragma unroll
            for (int j = 0; j < 4; ++j) {
                f16* dp = isA_[j] ? &As[ns][coff[j]] : &Bs[ns][coff[j]];
                __builtin_amdgcn_global_load_lds(
                    (const __attribute__((address_space(1))) unsigned int*)(gb[j] + kn),
                    (__attribute__((address_space(3))) unsigned int*)dp, 16, 0, 0);
            }
        }

        // ---- chunk0: af+bf retired; ag drains under MFMA ----
        asm volatile("s_waitcnt lgkmcnt(4)" ::: "memory");
        __builtin_amdgcn_sched_barrier(0);      // rule #18: MFMA must not hoist
        __builtin_amdgcn_s_setprio(1);
        #pragma unroll
        for (int i = 0; i < 4; ++i)
            #pragma unroll
            for (int j = 0; j < 4; ++j)
                acc[i][j] = __builtin_amdgcn_mfma_f32_16x16x32_f16(af[i], bf[j], acc[i][j], 0, 0, 0);
        __builtin_amdgcn_s_setprio(0);

        // ---- chunk1 ----
        asm volatile("s_waitcnt lgkmcnt(0)" ::: "memory");
        __builtin_amdgcn_sched_barrier(0);
        __builtin_amdgcn_s_setprio(1);
        #pragma unroll
        for (int i = 0; i < 4; ++i)
            #pragma unroll
            for (int j = 0; j < 4; ++j)
                acc[4 + i][j] = __builtin_amdgcn_mfma_f32_16x16x32_f16(ag[i], bf[j], acc[4 + i][j], 0, 0, 0);
        __builtin_amdgcn_s_setprio(0);
    }

    // C/D layout: col=lane&15, row=(lane>>4)*4+reg  [m89-verified]
    float* Cp = C + (size_t)lz * plane;
    #pragma unroll
    for (int i = 0; i < 8; ++i) {
        int row = m0 + wm + i * 16 + (lane >> 4) * 4;
        #pragma unroll
        for (int j = 0; j < 4; ++j) {
            int col = n0 + wn + j * 16 + lr;
            #pragma unroll
            for (int rr = 0; rr < 4; ++rr)
                Cp[(size_t)(row + rr) * N + col] = acc[i][j][rr];
        }
    }
}

// ---------------------------------------------------------------------------
// Fallback fp32 GEMM (round-1 verified, used only if ws_size tiny)
// ---------------------------------------------------------------------------
__global__ __launch_bounds__(256) void kan_gemm(
    const float* __restrict__ X, const float* __restrict__ BW,
    const float* __restrict__ SW, float* __restrict__ Y, int KIN, int OUT)
{
    __shared__ __align__(16) float Asf[72][68];
    __shared__ __align__(16) float Bsf[72][68];
    const int tid = threadIdx.x;
    const int n0 = blockIdx.x * 64;
    const int m0 = blockIdx.y * 64;
    const int tx = tid & 15;
    const int ty = tid >> 4;
    float acc[4][4] = {};
    for (int k0 = 0; k0 < KIN; k0 += 8) {
        #pragma unroll
        for (int rep = 0; rep < 2; ++rep) {
            int idx = rep * 256 + tid;
            int r = idx >> 3, c = idx & 7;
            float x = X[(size_t)(m0 + r) * KIN + k0 + c];
            int bk = c * 9;
            Asf[bk][r] = x;
            #pragma unroll
            for (int z = 0; z < 8; ++z) Asf[bk + 1 + z][r] = 0.0f;
            float xs = (x + 2.2f) * 2.5f;
            float fj = floorf(xs);
            int j = (int)fj;
            if (j >= 0 && j <= 10) {
                float t = xs - fj;
                float t2 = t * t, t3 = t2 * t;
                float omt = 1.0f - t;
                float p0 = omt * omt * omt * (1.0f / 6.0f);
                float p1 = (3.0f * t3 - 6.0f * t2 + 4.0f) * (1.0f / 6.0f);
                float p2 = (-3.0f * t3 + 3.0f * t2 + 3.0f * t + 1.0f) * (1.0f / 6.0f);
                float p3 = t3 * (1.0f / 6.0f);
                if (j >= 3) Asf[bk + 1 + j - 3][r] = p0;
                if (j >= 2 && j <= 9) Asf[bk + 1 + j - 2][r] = p1;
                if (j >= 1 && j <= 8) Asf[bk + 1 + j - 1][r] = p2;
                if (j <= 7) Asf[bk + 1 + j][r] = p3;
            }
        }
        #pragma unroll
        for (int rep = 0; rep < 16; ++rep) {
            int idx = rep * 256 + tid;
            int ol = idx >> 6;
            int l = idx & 63;
            int i = l >> 3, cc = l & 7;
            float v = SW[((size_t)(n0 + ol) * KIN + k0 + i) * 8 + cc];
            Bsf[i * 9 + 1 + cc][ol] = rintf(v * 32.0f) * 0.03125f;
        }
        #pragma unroll
        for (int rep = 0; rep < 2; ++rep) {
            int idx = rep * 256 + tid;
            int ol = idx >> 3, cc = idx & 7;
            Bsf[cc * 9][ol] = BW[(size_t)(n0 + ol) * KIN + k0 + cc];
        }
        __syncthreads();
        #pragma unroll 8
        for (int kk = 0; kk < 72; ++kk) {
            float4 av = *(const float4*)&Asf[kk][ty * 4];
            float4 bv = *(const float4*)&Bsf[kk][tx * 4];
            acc[0][0] += av.x * bv.x; acc[0][1] += av.x * bv.y; acc[0][2] += av.x * bv.z; acc[0][3] += av.x * bv.w;
            acc[1][0] += av.y * bv.x; acc[1][1] += av.y * bv.y; acc[1][2] += av.y * bv.z; acc[1][3] += av.y * bv.w;
            acc[2][0] += av.z * bv.x; acc[2][1] += av.z * bv.y; acc[2][2] += av.z * bv.z; acc[2][3] += av.z * bv.w;
            acc[3][0] += av.w * bv.x; acc[3][1] += av.w * bv.y; acc[3][2] += av.w * bv.z; acc[3][3] += av.w * bv.w;
        }
        __syncthreads();
    }
    #pragma unroll
    for (int i = 0; i < 4; ++i) {
        float4 o = make_float4(acc[i][0], acc[i][1], acc[i][2], acc[i][3]);
        *(float4*)&Y[(size_t)(m0 + ty * 4 + i) * OUT + n0 + tx * 4] = o;
    }
}

// ---------------------------------------------------------------------------
// huxley_rd (round-1 verified core); input = sum of S partial planes.
// ---------------------------------------------------------------------------
__device__ __forceinline__ float block_reduce_sum(float v, float* red, int tid) {
    red[tid] = v; __syncthreads();
    #pragma unroll
    for (int s = 128; s > 0; s >>= 1) {
        if (tid < s) red[tid] += red[tid + s];
        __syncthreads();
    }
    float r = red[0]; __syncthreads();
    return r;
}
__device__ __forceinline__ float block_reduce_min(float v, float* red, int tid) {
    red[tid] = v; __syncthreads();
    #pragma unroll
    for (int s = 128; s > 0; s >>= 1) {
        if (tid < s) red[tid] = fminf(red[tid], red[tid + s]);
        __syncthreads();
    }
    float r = red[0]; __syncthreads();
    return r;
}

__device__ void fft1024(float2* X, const float2* tw, int tid, bool inverse) {
    if (!inverse) {
        for (int sh = 9; sh >= 0; --sh) {
            int h = 1 << sh;
            #pragma unroll
            for (int q = 0; q < 2; ++q) {
                int b = tid + q * 256;
                int g = b >> sh, j = b & (h - 1);
                int i0 = (g << (sh + 1)) + j, i1 = i0 + h;
                float2 u = X[i0], v = X[i1];
                float dx = u.x - v.x, dy = u.y - v.y;
                X[i0] = make_float2(u.x + v.x, u.y + v.y);
                float2 w = tw[j << (9 - sh)];
                X[i1] = make_float2(dx * w.x + dy * w.y, dy * w.x - dx * w.y);
            }
            __syncthreads();
        }
    } else {
        for (int sh = 0; sh <= 9; ++sh) {
            int h = 1 << sh;
            #pragma unroll
            for (int q = 0; q < 2; ++q) {
                int b = tid + q * 256;
                int g = b >> sh, j = b & (h - 1);
                int i0 = (g << (sh + 1)) + j, i1 = i0 + h;
                float2 u = X[i0], v = X[i1];
                float2 w = tw[j << (9 - sh)];
                float tx2 = v.x * w.x - v.y * w.y;
                float ty2 = v.x * w.y + v.y * w.x;
                X[i0] = make_float2(u.x + tx2, u.y + ty2);
                X[i1] = make_float2(u.x - tx2, u.y - ty2);
            }
            __syncthreads();
        }
    }
}

__global__ __launch_bounds__(256) void huxley_kernel(
    const float* __restrict__ Pin, size_t plane, int S,
    float* __restrict__ dst,
    const float* __restrict__ sg, const float* __restrict__ dk,
    const float* __restrict__ pa, const float* __restrict__ pgam,
    const float* __restrict__ ptau, const float* __restrict__ pvel,
    const float* __restrict__ gp, const float* __restrict__ chi)
{
    __shared__ float2 A[1024];
    __shared__ float2 Bb[1024];
    __shared__ float sErg[1024];
    __shared__ float sAbs[516];
    __shared__ float2 tw[512];
    __shared__ float red[256];
    __shared__ float sG[516];

    const int tid = threadIdx.x;
    const int row = blockIdx.x;
    const float* pin = Pin + (size_t)row * 1024;
    float* uo = dst + (size_t)row * 1024;

    for (int m = tid; m < 512; m += 256) {
        float s, c;
        sincosf(6.283185307179586f * (float)m * (1.0f / 1024.0f), &s, &c);
        tw[m] = make_float2(c, s);
    }
    for (int k = tid; k < 513; k += 256)
        sG[k] = 1.0f / (1.0f + expf(-sg[k]));
    for (int i = tid; i < 1024; i += 256) {
        float s = 0.0f;
        for (int ss = 0; ss < S; ++ss) s += pin[(size_t)ss * plane + i];
        A[i] = make_float2(s, 0.0f);
    }
    __syncthreads();

    fft1024(A, tw, tid, false);

    for (int p = tid; p < 1024; p += 256) {
        int k = (int)(__brev((unsigned)p) >> 22);
        int m = (k <= 512) ? k : 1024 - k;
        float g = sG[m] * (1.0f / 1024.0f);
        Bb[p] = make_float2(A[p].x * g, A[p].y * g);
    }
    __syncthreads();
    fft1024(Bb, tw, tid, true);
    for (int i = tid; i < 1024; i += 256) sErg[i] = Bb[i].x;
    __syncthreads();

    const float vv = pvel[0];
    for (int p = tid; p < 1024; p += 256) {
        int k = (int)(__brev((unsigned)p) >> 22);
        int m = (k <= 512) ? k : 1024 - k;
        float omg = 1.0f - sG[m];
        float nx = A[p].x * omg, ny = A[p].y * omg;
        float ang = (k <= 512)
            ? (-6.283185307179586f * vv * (float)k * (1.0f / 1024.0f))
            : (6.283185307179586f * vv * (float)(1024 - k) * (1.0f / 1024.0f));
        float sn, cs;
        sincosf(ang, &sn, &cs);
        float yx = nx * cs - ny * sn;
        float yy = nx * sn + ny * cs;
        if (k < 512)       sAbs[k]   = sqrtf(nx * nx + ny * ny);
        else if (k == 512) sAbs[512] = fabsf(yx);
        Bb[p] = make_float2(yx * (1.0f / 1024.0f), yy * (1.0f / 1024.0f));
    }
    __syncthreads();
    fft1024(Bb, tw, tid, true);

    float loc = 0.0f;
    for (int i = tid; i < 1024; i += 256) { float x = Bb[i].x; loc += x * x; }
    float trc = block_reduce_sum(loc, red, tid);

    loc = 0.0f;
    for (int k = tid; k < 513; k += 256) loc += sAbs[k];
    float mean = block_reduce_sum(loc, red, tid) * (1.0f / 513.0f);

    loc = 0.0f;
    for (int k = tid; k < 513; k += 256) { float d = sAbs[k] - mean; loc += d * d; }
    float varsum = block_reduce_sum(loc, red, tid);

    loc = 3.4e38f;
    for (int k = tid; k < 513; k += 256) loc = fminf(loc, sAbs[k]);
    float lmin = block_reduce_min(loc, red, tid);

    float det_pas = varsum * (1.0f / 512.0f) + 1e-6f;
    float sd = sqrtf(det_pas);
    float denom = 2.0f * sd * sd * sd + 1e-8f;
    float c3 = (3.0f * gp[row] - trc / ptau[0]) / denom;
    c3 = fminf(fmaxf(c3, -0.999f), 0.999f);
    float ph = acosf(c3) * (1.0f / 3.0f);
    float amp = 2.0f * sqrtf(lmin * (1.0f / 3.0f) + 1e-8f);
    float nu = sqrtf(trc);
    float achi = fabsf(chi[row]);
    float cbest = 0.0f, ebest = -1.0f;
    #pragma unroll
    for (int kb = 0; kb < 3; ++kb) {
        float ck = amp * cosf(ph + 2.0943951023931953f * (float)kb) * expf(-achi * (float)kb);
        float ek = fabsf(ck) * nu;
        if (ek > ebest) { ebest = ek; cbest = ck; }
    }

    const float a = pa[0], gm = pgam[0];
    const float k0 = dk[0], k1 = dk[1], k2 = dk[2];
    for (int i = tid; i < 1024; i += 256) {
        float e = sErg[i];
        float l = (i > 0) ? sErg[i - 1] : 0.0f;
        float r = (i < 1023) ? sErg[i + 1] : 0.0f;
        float reac = e * (e - a) * (1.0f - e);
        float diff = k0 * l + k1 * e + k2 * r;
        float un = e + 0.1f * (reac + gm * diff);
        float s = un + cbest * Bb[i].x;
        uo[i] = s / (1.0f + expf(-s));
    }
}

// ---------------------------------------------------------------------------

extern "C" void kernel_launch(void* const* d_in, const int* in_sizes, int n_in,
                              void* d_out, int out_size, void* d_ws, size_t ws_size,
                              hipStream_t stream) {
    const float* c    = (const float*)d_in[0];
    const float* bw0  = (const float*)d_in[1];
    const float* sw0  = (const float*)d_in[2];
    const float* bw1  = (const float*)d_in[3];
    const float* sw1  = (const float*)d_in[4];
    const float* bw2  = (const float*)d_in[5];
    const float* sw2  = (const float*)d_in[6];
    const float* sg   = (const float*)d_in[7];
    const float* dk   = (const float*)d_in[8];
    const float* pa   = (const float*)d_in[9];
    const float* pgam = (const float*)d_in[10];
    const float* ptau = (const float*)d_in[11];
    const float* pvel = (const float*)d_in[12];
    const float* gp   = (const float*)d_in[13];
    const float* chi  = (const float*)d_in[14];

    const int B = 4096, NIN = 512, W = 1024, NOUT = 1024;
    const int KE0 = 19 * NIN, KE1 = 19 * W;
    const size_t MN = (size_t)B * W;
    const size_t BE = (size_t)W * KE1 * 2;      // Bexp bytes (39.85 MB)
    dim3 blk(256);
    dim3 gblk(512);

    // ---- pick (CH, S): 256-row m-tiles; {4096,4} -> gemm grid 4x16x4 = 256 = 1/CU ----
    struct Cand { int CH, S; };
    const Cand cands[] = {
        {4096, 4}, {4096, 3}, {2048, 4}, {2048, 3}, {1024, 4},
        {512, 4}, {256, 4}
    };
    int CH = 0, S = 1;
    for (const auto& cd : cands) {
        size_t need = BE + (size_t)cd.CH * KE1 * 2 + (size_t)cd.S * MN * 4;
        if (need <= ws_size) { CH = cd.CH; S = cd.S; break; }
    }

    if (CH > 0) {
        f16* Bexp = (f16*)d_ws;
        float* P  = (float*)((char*)d_ws + BE);                // S planes of M x N fp32
        f16* Aexp = (f16*)((char*)d_ws + BE + (size_t)S * MN * 4);

        // ceil-split Kc (multiple of 32); kernel clamps last split
        const int Kc0 = ((KE0 / 32 + S - 1) / S) * 32;
        const int Kc1 = ((KE1 / 32 + S - 1) / S) * 32;

        // ---- layer 0: KIN=512 ----
        prep_b<<<(W * NIN) / 256, blk, 0, stream>>>(bw0, sw0, Bexp, NIN, 9);
        for (int r0 = 0; r0 < B; r0 += CH) {
            expand_sum_a<<<(CH * NIN) / 256, blk, 0, stream>>>(
                c + (size_t)r0 * NIN, 0, 1, Aexp, NIN, 9);
            gemm_mfma<<<dim3(W / 256, CH / 256, S), gblk, 0, stream>>>(
                Aexp, Bexp, P + (size_t)r0 * W, KE0, Kc0, MN, W);
        }
        // ---- layer 1: KIN=1024 ----
        prep_b<<<(W * W) / 256, blk, 0, stream>>>(bw1, sw1, Bexp, W, 10);
        for (int r0 = 0; r0 < B; r0 += CH) {
            expand_sum_a<<<(CH * W) / 256, blk, 0, stream>>>(
                P + (size_t)r0 * W, MN, S, Aexp, W, 10);
            gemm_mfma<<<dim3(W / 256, CH / 256, S), gblk, 0, stream>>>(
                Aexp, Bexp, P + (size_t)r0 * W, KE1, Kc1, MN, W);
        }
        // ---- layer 2 ----
        prep_b<<<(NOUT * W) / 256, blk, 0, stream>>>(bw2, sw2, Bexp, W, 10);
        for (int r0 = 0; r0 < B; r0 += CH) {
            expand_sum_a<<<(CH * W) / 256, blk, 0, stream>>>(
                P + (size_t)r0 * W, MN, S, Aexp, W, 10);
            gemm_mfma<<<dim3(NOUT / 256, CH / 256, S), gblk, 0, stream>>>(
                Aexp, Bexp, P + (size_t)r0 * W, KE1, Kc1, MN, NOUT);
        }
        huxley_kernel<<<B, blk, 0, stream>>>(P, MN, S, (float*)d_out,
                                             sg, dk, pa, pgam, ptau, pvel, gp, chi);
    } else {
        // fallback: round-1 fp32 path (needs only 33.6 MB ws)
        float* fx0 = (float*)d_ws;
        float* fx1 = fx0 + (size_t)B * W;
        dim3 g0(W / 64, B / 64);
        kan_gemm<<<g0, blk, 0, stream>>>(c,   bw0, sw0, fx0, NIN, W);
        kan_gemm<<<g0, blk, 0, stream>>>(fx0, bw1, sw1, fx1, W,   W);
        dim3 g2(NOUT / 64, B / 64);
        kan_gemm<<<g2, blk, 0, stream>>>(fx1, bw2, sw2, (float*)d_out, W, NOUT);
        huxley_kernel<<<B, blk, 0, stream>>>((float*)d_out, 0, 1, (float*)d_out,
                                             sg, dk, pa, pgam, ptau, pvel, gp, chi);
    }
}

// Round 5
// 690.825 us; speedup vs baseline: 1.0110x; 1.0110x over previous
//
#include <hip/hip_runtime.h>
#include <math.h>

typedef _Float16 f16;
typedef _Float16 f16x8 __attribute__((ext_vector_type(8)));
typedef float f32x4 __attribute__((ext_vector_type(4)));

// ---------------------------------------------------------------------------
// expand_sum_a: x[b,i] = sum_{s<Sin} src[s*plane + b*KIN + i]  (Sin=1: raw input)
// -> Aexp (rows x KIN*19 fp16)
// planes per row: [0,8K): basis-hi | [8K,16K): basis-lo | xh | xh | xl
// ---------------------------------------------------------------------------
__global__ __launch_bounds__(256) void expand_sum_a(
    const float* __restrict__ src, size_t plane, int Sin,
    f16* __restrict__ Aexp, int KIN, int shift)
{
    int idx = blockIdx.x * 256 + threadIdx.x;
    int i = idx & (KIN - 1);
    int b = idx >> shift;
    float x = 0.0f;
    for (int s = 0; s < Sin; ++s) x += src[(size_t)s * plane + idx];

    float xs = (x + 2.2f) * 2.5f;
    float fj = floorf(xs);
    int jj = (int)fj;
    float t = xs - fj;
    float t2 = t * t, t3 = t2 * t;
    float omt = 1.0f - t;
    float p0 = omt * omt * omt * (1.0f / 6.0f);
    float p1 = (3.0f * t3 - 6.0f * t2 + 4.0f) * (1.0f / 6.0f);
    float p2 = (-3.0f * t3 + 3.0f * t2 + 3.0f * t + 1.0f) * (1.0f / 6.0f);
    float p3 = t3 * (1.0f / 6.0f);

    union { f16 h[8]; uint4 v; } hi, lo;
    bool inr = (jj >= 0 && jj <= 10);
    #pragma unroll
    for (int cc = 0; cc < 8; ++cc) {
        int d = cc - (jj - 3);
        float v = 0.0f;
        if (inr) {
            if (d == 0) v = p0; else if (d == 1) v = p1;
            else if (d == 2) v = p2; else if (d == 3) v = p3;
        }
        f16 h = (f16)v;
        hi.h[cc] = h;
        lo.h[cc] = (f16)(v - (float)h);
    }
    size_t KEXP = (size_t)KIN * 19;
    f16* row = Aexp + (size_t)b * KEXP;
    *(uint4*)(row + (size_t)i * 8) = hi.v;
    *(uint4*)(row + (size_t)KIN * 8 + (size_t)i * 8) = lo.v;
    f16 xh = (f16)x;
    f16 xl = (f16)(x - (float)xh);
    int K16 = KIN * 16;
    row[K16 + i] = xh;
    row[K16 + KIN + i] = xh;
    row[K16 + 2 * KIN + i] = xl;
}

// ---------------------------------------------------------------------------
// prep_b (round-3 verified): planes [qw x8][qw x8][wh][wl][wh]
// pairing with A: (bh+bl)*qw + xh*wh + xh*wl + xl*wh
// ---------------------------------------------------------------------------
__global__ __launch_bounds__(256) void prep_b(
    const float* __restrict__ BW, const float* __restrict__ SW,
    f16* __restrict__ Bexp, int KIN, int shift)
{
    int idx = blockIdx.x * 256 + threadIdx.x;
    int i = idx & (KIN - 1);
    int o = idx >> shift;
    const float* sp = SW + ((size_t)o * KIN + i) * 8;
    union { f16 h[8]; uint4 v; } pk;
    #pragma unroll
    for (int cc = 0; cc < 8; ++cc)
        pk.h[cc] = (f16)(rintf(sp[cc] * 32.0f) * 0.03125f);  // n/32, exact in fp16
    size_t KEXP = (size_t)KIN * 19;
    f16* row = Bexp + (size_t)o * KEXP;
    *(uint4*)(row + (size_t)i * 8) = pk.v;
    *(uint4*)(row + (size_t)KIN * 8 + (size_t)i * 8) = pk.v;
    float w = BW[(size_t)o * KIN + i];
    f16 wh = (f16)w;
    f16 wl = (f16)(w - (float)wh);
    int K16 = KIN * 16;
    row[K16 + i] = wh;
    row[K16 + KIN + i] = wl;
    row[K16 + 2 * KIN + i] = wh;
}

// ---------------------------------------------------------------------------
// gemm_mfma R12: 256x256 block tile, 512 threads / 8 waves (2M x 4N), wave
// tile 128x64. BK=64, 2-slot LDS ring (2 x 64KB), prefetch distance 1.
// ONE barrier per 64-K tile (halves rendezvous vs BK=32); per tile 4 MFMA
// chunks x 16 with counted lgkm pipelining (each read batch drains under
// the previous MFMA chunk):
//   [af0,bf0(8)][ag0(4)][gload 0-3] lgkm(4) c0 | [af1,bf1(8)] lgkm(8) c1 |
//   [ag1(4)][gload 4-7] lgkm(4) c2 | lgkm(0) c3 | vmcnt(0) barrier
// R4 post-mortem: barrier between reads and MFMA re-locksteps (43.5%);
// R3 placement (reads at tile top, post-barrier, wave-skewed) kept here.
// vmcnt(0) at tile end is cheap: gloads issued >=1200 cyc before the wait
// (> 900cyc HBM latency), so the drain is residual-only.
// Sync ledger (audited):
//   fill: tile t (slot t&1) loaded by gloads issued during t-1 (or prologue);
//         vmcnt(0)+barrier at end of t-1 makes it resident for all waves.
//   overwrite: gloads during t write slot (t+1)&1 which held tile t-1; all
//         waves' t-1 reads completed (own lgkm(0)) before end-of-(t-1)
//         barrier; gloads issue after it -> no pending readers.
//   lgkm in-order retirement: batches separated by sched_barrier(0);
//         lgkm(4)->af0,bf0; lgkm(8)->ag0; lgkm(4)->af1,bf1; lgkm(0)->ag1.
// Swizzle (re-derived for 128B rows, 8 x 16B slots/row):
//   phys slot at (row, kc) holds global kc ^ (row&7).
//   staging: linear LDS dest; per-lane global kc_src = (lane&7)^((lane>>3)&7)
//            (involution; octet-coalesced 128B global segments).
//   reads: phys = (ks*4 + (lane>>4)) ^ (lr&7); octet bank audit: lanes 0-7
//          hit 8 distinct 16B slots (rows 128B-aligned) -> conflict-free.
// XCD-bijective block swizzle: L = (b&7)*q + (b>>3) enumerated x-fastest.
// ---------------------------------------------------------------------------
__global__ __launch_bounds__(512, 2) void gemm_mfma(
    const f16* __restrict__ A, const f16* __restrict__ Bm,
    float* __restrict__ C, int Kfull, int Kc, size_t plane, int N)
{
    __shared__ __align__(16) f16 As[2][16384];   // [slot][256 rows x 64 k], 128B rows
    __shared__ __align__(16) f16 Bs[2][16384];   // [slot][256 rows x 64 k]

    const int tid = threadIdx.x;
    const int wave = tid >> 6, lane = tid & 63;

    // ---- XCD-aware bijective swizzle (nwg % 8 == 0 for all CH/S candidates) ----
    const int nwg = gridDim.x * gridDim.y * gridDim.z;
    const int b = blockIdx.x + gridDim.x * (blockIdx.y + gridDim.y * blockIdx.z);
    const int q = nwg >> 3;
    const int L = (b & 7) * q + (b >> 3);
    const int lx = L % gridDim.x;
    const int rest = L / gridDim.x;
    const int ly = rest % gridDim.y;
    const int lz = rest / gridDim.y;

    const int m0 = ly * 256, n0 = lx * 256;
    const int kb = lz * Kc;
    int kcl = Kfull - kb; if (kcl > Kc) kcl = Kc;
    const int NT = kcl >> 6;

    // staging: 64 chunks of 1KB per BK=64 tile (A:0..31, B:32..63); wave owns 8.
    // chunk c8 covers 8 rows (128B each); lane l -> row c8*8 + (l>>3),
    // phys slot (l&7); global k-chunk kc_src = (l&7) ^ ((l>>3)&7).
    const int kc_src = (lane & 7) ^ ((lane >> 3) & 7);
    const f16* gb[8];
    int isA_[8], coff[8];
    #pragma unroll
    for (int j = 0; j < 8; ++j) {
        int cch = wave * 8 + j;
        int a = (cch < 32);
        int c8 = a ? cch : (cch - 32);
        int row0 = (a ? m0 : n0) + c8 * 8 + (lane >> 3);
        gb[j] = (a ? A : Bm) + (size_t)row0 * Kfull + kb + kc_src * 8;
        isA_[j] = a;
        coff[j] = c8 * 512;   // f16 offset: 8 rows x 64
    }

    f32x4 acc[8][4];
    #pragma unroll
    for (int i = 0; i < 8; ++i)
        #pragma unroll
        for (int j = 0; j < 4; ++j)
            acc[i][j] = (f32x4){0.f, 0.f, 0.f, 0.f};

    // prologue: tile 0 -> slot 0
    #pragma unroll
    for (int j = 0; j < 8; ++j) {
        f16* dp = isA_[j] ? &As[0][coff[j]] : &Bs[0][coff[j]];
        __builtin_amdgcn_global_load_lds(
            (const __attribute__((address_space(1))) unsigned int*)(gb[j]),
            (__attribute__((address_space(3))) unsigned int*)dp, 16, 0, 0);
    }
    asm volatile("s_waitcnt vmcnt(0)" ::: "memory");
    __builtin_amdgcn_s_barrier();
    asm volatile("" ::: "memory");

    const int lr = lane & 15;
    const int g4 = lane >> 4;                       // 0..3 (k-group within K=32)
    const int ko0 = ((g4     ^ (lr & 7))) * 8;      // ks=0 phys slot -> f16 off
    const int ko1 = (((4|g4) ^ (lr & 7))) * 8;      // ks=1 (4+g4)
    const int wm = (wave & 1) * 128, wn = (wave >> 1) * 64;

    for (int t = 0; t < NT; ++t) {
        const int st = t & 1;
        const int ns = st ^ 1;
        const bool pf = (t + 1 < NT);
        const int kt = (t + 1) << 6;

        f16x8 af0[4], bf0[4], ag0[4], af1[4], bf1[4], ag1[4];

        // batch R0: af0 + bf0 (8 reads)
        #pragma unroll
        for (int i = 0; i < 4; ++i)
            af0[i] = *(const f16x8*)&As[st][(wm + i * 16 + lr) * 64 + ko0];
        #pragma unroll
        for (int j = 0; j < 4; ++j)
            bf0[j] = *(const f16x8*)&Bs[st][(wn + j * 16 + lr) * 64 + ko0];
        __builtin_amdgcn_sched_barrier(0);
        // batch R1: ag0 (4 reads)
        #pragma unroll
        for (int i = 0; i < 4; ++i)
            ag0[i] = *(const f16x8*)&As[st][(wm + 64 + i * 16 + lr) * 64 + ko0];
        __builtin_amdgcn_sched_barrier(0);
        // first half of next tile's staging
        if (pf) {
            #pragma unroll
            for (int j = 0; j < 4; ++j) {
                f16* dp = isA_[j] ? &As[ns][coff[j]] : &Bs[ns][coff[j]];
                __builtin_amdgcn_global_load_lds(
                    (const __attribute__((address_space(1))) unsigned int*)(gb[j] + kt),
                    (__attribute__((address_space(3))) unsigned int*)dp, 16, 0, 0);
            }
        }

        // ---- c0: af0 x bf0 (ag0 drains underneath) ----
        asm volatile("s_waitcnt lgkmcnt(4)" ::: "memory");
        __builtin_amdgcn_sched_barrier(0);
        __builtin_amdgcn_s_setprio(1);
        #pragma unroll
        for (int i = 0; i < 4; ++i)
            #pragma unroll
            for (int j = 0; j < 4; ++j)
                acc[i][j] = __builtin_amdgcn_mfma_f32_16x16x32_f16(af0[i], bf0[j], acc[i][j], 0, 0, 0);
        __builtin_amdgcn_s_setprio(0);

        // batch R2: af1 + bf1 (8 reads, drain under c1)
        #pragma unroll
        for (int i = 0; i < 4; ++i)
            af1[i] = *(const f16x8*)&As[st][(wm + i * 16 + lr) * 64 + ko1];
        #pragma unroll
        for (int j = 0; j < 4; ++j)
            bf1[j] = *(const f16x8*)&Bs[st][(wn + j * 16 + lr) * 64 + ko1];
        __builtin_amdgcn_sched_barrier(0);

        // ---- c1: ag0 x bf0 ----
        asm volatile("s_waitcnt lgkmcnt(8)" ::: "memory");
        __builtin_amdgcn_sched_barrier(0);
        __builtin_amdgcn_s_setprio(1);
        #pragma unroll
        for (int i = 0; i < 4; ++i)
            #pragma unroll
            for (int j = 0; j < 4; ++j)
                acc[4 + i][j] = __builtin_amdgcn_mfma_f32_16x16x32_f16(ag0[i], bf0[j], acc[4 + i][j], 0, 0, 0);
        __builtin_amdgcn_s_setprio(0);

        // batch R3: ag1 (4 reads) + second half staging
        #pragma unroll
        for (int i = 0; i < 4; ++i)
            ag1[i] = *(const f16x8*)&As[st][(wm + 64 + i * 16 + lr) * 64 + ko1];
        __builtin_amdgcn_sched_barrier(0);
        if (pf) {
            #pragma unroll
            for (int j = 4; j < 8; ++j) {
                f16* dp = isA_[j] ? &As[ns][coff[j]] : &Bs[ns][coff[j]];
                __builtin_amdgcn_global_load_lds(
                    (const __attribute__((address_space(1))) unsigned int*)(gb[j] + kt),
                    (__attribute__((address_space(3))) unsigned int*)dp, 16, 0, 0);
            }
        }

        // ---- c2: af1 x bf1 (ag1 drains underneath) ----
        asm volatile("s_waitcnt lgkmcnt(4)" ::: "memory");
        __builtin_amdgcn_sched_barrier(0);
        __builtin_amdgcn_s_setprio(1);
        #pragma unroll
        for (int i = 0; i < 4; ++i)
            #pragma unroll
            for (int j = 0; j < 4; ++j)
                acc[i][j] = __builtin_amdgcn_mfma_f32_16x16x32_f16(af1[i], bf1[j], acc[i][j], 0, 0, 0);
        __builtin_amdgcn_s_setprio(0);

        // ---- c3: ag1 x bf1 ----
        asm volatile("s_waitcnt lgkmcnt(0)" ::: "memory");
        __builtin_amdgcn_sched_barrier(0);
        __builtin_amdgcn_s_setprio(1);
        #pragma unroll
        for (int i = 0; i < 4; ++i)
            #pragma unroll
            for (int j = 0; j < 4; ++j)
                acc[4 + i][j] = __builtin_amdgcn_mfma_f32_16x16x32_f16(ag1[i], bf1[j], acc[4 + i][j], 0, 0, 0);
        __builtin_amdgcn_s_setprio(0);

        // ---- end-of-tile: next tile resident for all waves ----
        if (pf) {
            asm volatile("s_waitcnt vmcnt(0)" ::: "memory");
            __builtin_amdgcn_sched_barrier(0);
            __builtin_amdgcn_s_barrier();
            asm volatile("" ::: "memory");
        }
    }

    // C/D layout: col=lane&15, row=(lane>>4)*4+reg  [m89-verified]
    float* Cp = C + (size_t)lz * plane;
    #pragma unroll
    for (int i = 0; i < 8; ++i) {
        int row = m0 + wm + i * 16 + (lane >> 4) * 4;
        #pragma unroll
        for (int j = 0; j < 4; ++j) {
            int col = n0 + wn + j * 16 + lr;
            #pragma unroll
            for (int rr = 0; rr < 4; ++rr)
                Cp[(size_t)(row + rr) * N + col] = acc[i][j][rr];
        }
    }
}

// ---------------------------------------------------------------------------
// Fallback fp32 GEMM (round-1 verified, used only if ws_size tiny)
// ---------------------------------------------------------------------------
__global__ __launch_bounds__(256) void kan_gemm(
    const float* __restrict__ X, const float* __restrict__ BW,
    const float* __restrict__ SW, float* __restrict__ Y, int KIN, int OUT)
{
    __shared__ __align__(16) float Asf[72][68];
    __shared__ __align__(16) float Bsf[72][68];
    const int tid = threadIdx.x;
    const int n0 = blockIdx.x * 64;
    const int m0 = blockIdx.y * 64;
    const int tx = tid & 15;
    const int ty = tid >> 4;
    float acc[4][4] = {};
    for (int k0 = 0; k0 < KIN; k0 += 8) {
        #pragma unroll
        for (int rep = 0; rep < 2; ++rep) {
            int idx = rep * 256 + tid;
            int r = idx >> 3, c = idx & 7;
            float x = X[(size_t)(m0 + r) * KIN + k0 + c];
            int bk = c * 9;
            Asf[bk][r] = x;
            #pragma unroll
            for (int z = 0; z < 8; ++z) Asf[bk + 1 + z][r] = 0.0f;
            float xs = (x + 2.2f) * 2.5f;
            float fj = floorf(xs);
            int j = (int)fj;
            if (j >= 0 && j <= 10) {
                float t = xs - fj;
                float t2 = t * t, t3 = t2 * t;
                float omt = 1.0f - t;
                float p0 = omt * omt * omt * (1.0f / 6.0f);
                float p1 = (3.0f * t3 - 6.0f * t2 + 4.0f) * (1.0f / 6.0f);
                float p2 = (-3.0f * t3 + 3.0f * t2 + 3.0f * t + 1.0f) * (1.0f / 6.0f);
                float p3 = t3 * (1.0f / 6.0f);
                if (j >= 3) Asf[bk + 1 + j - 3][r] = p0;
                if (j >= 2 && j <= 9) Asf[bk + 1 + j - 2][r] = p1;
                if (j >= 1 && j <= 8) Asf[bk + 1 + j - 1][r] = p2;
                if (j <= 7) Asf[bk + 1 + j][r] = p3;
            }
        }
        #pragma unroll
        for (int rep = 0; rep < 16; ++rep) {
            int idx = rep * 256 + tid;
            int ol = idx >> 6;
            int l = idx & 63;
            int i = l >> 3, cc = l & 7;
            float v = SW[((size_t)(n0 + ol) * KIN + k0 + i) * 8 + cc];
            Bsf[i * 9 + 1 + cc][ol] = rintf(v * 32.0f) * 0.03125f;
        }
        #pragma unroll
        for (int rep = 0; rep < 2; ++rep) {
            int idx = rep * 256 + tid;
            int ol = idx >> 3, cc = idx & 7;
            Bsf[cc * 9][ol] = BW[(size_t)(n0 + ol) * KIN + k0 + cc];
        }
        __syncthreads();
        #pragma unroll 8
        for (int kk = 0; kk < 72; ++kk) {
            float4 av = *(const float4*)&Asf[kk][ty * 4];
            float4 bv = *(const float4*)&Bsf[kk][tx * 4];
            acc[0][0] += av.x * bv.x; acc[0][1] += av.x * bv.y; acc[0][2] += av.x * bv.z; acc[0][3] += av.x * bv.w;
            acc[1][0] += av.y * bv.x; acc[1][1] += av.y * bv.y; acc[1][2] += av.y * bv.z; acc[1][3] += av.y * bv.w;
            acc[2][0] += av.z * bv.x; acc[2][1] += av.z * bv.y; acc[2][2] += av.z * bv.z; acc[2][3] += av.z * bv.w;
            acc[3][0] += av.w * bv.x; acc[3][1] += av.w * bv.y; acc[3][2] += av.w * bv.z; acc[3][3] += av.w * bv.w;
        }
        __syncthreads();
    }
    #pragma unroll
    for (int i = 0; i < 4; ++i) {
        float4 o = make_float4(acc[i][0], acc[i][1], acc[i][2], acc[i][3]);
        *(float4*)&Y[(size_t)(m0 + ty * 4 + i) * OUT + n0 + tx * 4] = o;
    }
}

// ---------------------------------------------------------------------------
// huxley_rd (round-1 verified core); input = sum of S partial planes.
// ---------------------------------------------------------------------------
__device__ __forceinline__ float block_reduce_sum(float v, float* red, int tid) {
    red[tid] = v; __syncthreads();
    #pragma unroll
    for (int s = 128; s > 0; s >>= 1) {
        if (tid < s) red[tid] += red[tid + s];
        __syncthreads();
    }
    float r = red[0]; __syncthreads();
    return r;
}
__device__ __forceinline__ float block_reduce_min(float v, float* red, int tid) {
    red[tid] = v; __syncthreads();
    #pragma unroll
    for (int s = 128; s > 0; s >>= 1) {
        if (tid < s) red[tid] = fminf(red[tid], red[tid + s]);
        __syncthreads();
    }
    float r = red[0]; __syncthreads();
    return r;
}

__device__ void fft1024(float2* X, const float2* tw, int tid, bool inverse) {
    if (!inverse) {
        for (int sh = 9; sh >= 0; --sh) {
            int h = 1 << sh;
            #pragma unroll
            for (int q = 0; q < 2; ++q) {
                int b = tid + q * 256;
                int g = b >> sh, j = b & (h - 1);
                int i0 = (g << (sh + 1)) + j, i1 = i0 + h;
                float2 u = X[i0], v = X[i1];
                float dx = u.x - v.x, dy = u.y - v.y;
                X[i0] = make_float2(u.x + v.x, u.y + v.y);
                float2 w = tw[j << (9 - sh)];
                X[i1] = make_float2(dx * w.x + dy * w.y, dy * w.x - dx * w.y);
            }
            __syncthreads();
        }
    } else {
        for (int sh = 0; sh <= 9; ++sh) {
            int h = 1 << sh;
            #pragma unroll
            for (int q = 0; q < 2; ++q) {
                int b = tid + q * 256;
                int g = b >> sh, j = b & (h - 1);
                int i0 = (g << (sh + 1)) + j, i1 = i0 + h;
                float2 u = X[i0], v = X[i1];
                float2 w = tw[j << (9 - sh)];
                float tx2 = v.x * w.x - v.y * w.y;
                float ty2 = v.x * w.y + v.y * w.x;
                X[i0] = make_float2(u.x + tx2, u.y + ty2);
                X[i1] = make_float2(u.x - tx2, u.y - ty2);
            }
            __syncthreads();
        }
    }
}

__global__ __launch_bounds__(256) void huxley_kernel(
    const float* __restrict__ Pin, size_t plane, int S,
    float* __restrict__ dst,
    const float* __restrict__ sg, const float* __restrict__ dk,
    const float* __restrict__ pa, const float* __restrict__ pgam,
    const float* __restrict__ ptau, const float* __restrict__ pvel,
    const float* __restrict__ gp, const float* __restrict__ chi)
{
    __shared__ float2 A[1024];
    __shared__ float2 Bb[1024];
    __shared__ float sErg[1024];
    __shared__ float sAbs[516];
    __shared__ float2 tw[512];
    __shared__ float red[256];
    __shared__ float sG[516];

    const int tid = threadIdx.x;
    const int row = blockIdx.x;
    const float* pin = Pin + (size_t)row * 1024;
    float* uo = dst + (size_t)row * 1024;

    for (int m = tid; m < 512; m += 256) {
        float s, c;
        sincosf(6.283185307179586f * (float)m * (1.0f / 1024.0f), &s, &c);
        tw[m] = make_float2(c, s);
    }
    for (int k = tid; k < 513; k += 256)
        sG[k] = 1.0f / (1.0f + expf(-sg[k]));
    for (int i = tid; i < 1024; i += 256) {
        float s = 0.0f;
        for (int ss = 0; ss < S; ++ss) s += pin[(size_t)ss * plane + i];
        A[i] = make_float2(s, 0.0f);
    }
    __syncthreads();

    fft1024(A, tw, tid, false);

    for (int p = tid; p < 1024; p += 256) {
        int k = (int)(__brev((unsigned)p) >> 22);
        int m = (k <= 512) ? k : 1024 - k;
        float g = sG[m] * (1.0f / 1024.0f);
        Bb[p] = make_float2(A[p].x * g, A[p].y * g);
    }
    __syncthreads();
    fft1024(Bb, tw, tid, true);
    for (int i = tid; i < 1024; i += 256) sErg[i] = Bb[i].x;
    __syncthreads();

    const float vv = pvel[0];
    for (int p = tid; p < 1024; p += 256) {
        int k = (int)(__brev((unsigned)p) >> 22);
        int m = (k <= 512) ? k : 1024 - k;
        float omg = 1.0f - sG[m];
        float nx = A[p].x * omg, ny = A[p].y * omg;
        float ang = (k <= 512)
            ? (-6.283185307179586f * vv * (float)k * (1.0f / 1024.0f))
            : (6.283185307179586f * vv * (float)(1024 - k) * (1.0f / 1024.0f));
        float sn, cs;
        sincosf(ang, &sn, &cs);
        float yx = nx * cs - ny * sn;
        float yy = nx * sn + ny * cs;
        if (k < 512)       sAbs[k]   = sqrtf(nx * nx + ny * ny);
        else if (k == 512) sAbs[512] = fabsf(yx);
        Bb[p] = make_float2(yx * (1.0f / 1024.0f), yy * (1.0f / 1024.0f));
    }
    __syncthreads();
    fft1024(Bb, tw, tid, true);

    float loc = 0.0f;
    for (int i = tid; i < 1024; i += 256) { float x = Bb[i].x; loc += x * x; }
    float trc = block_reduce_sum(loc, red, tid);

    loc = 0.0f;
    for (int k = tid; k < 513; k += 256) loc += sAbs[k];
    float mean = block_reduce_sum(loc, red, tid) * (1.0f / 513.0f);

    loc = 0.0f;
    for (int k = tid; k < 513; k += 256) { float d = sAbs[k] - mean; loc += d * d; }
    float varsum = block_reduce_sum(loc, red, tid);

    loc = 3.4e38f;
    for (int k = tid; k < 513; k += 256) loc = fminf(loc, sAbs[k]);
    float lmin = block_reduce_min(loc, red, tid);

    float det_pas = varsum * (1.0f / 512.0f) + 1e-6f;
    float sd = sqrtf(det_pas);
    float denom = 2.0f * sd * sd * sd + 1e-8f;
    float c3 = (3.0f * gp[row] - trc / ptau[0]) / denom;
    c3 = fminf(fmaxf(c3, -0.999f), 0.999f);
    float ph = acosf(c3) * (1.0f / 3.0f);
    float amp = 2.0f * sqrtf(lmin * (1.0f / 3.0f) + 1e-8f);
    float nu = sqrtf(trc);
    float achi = fabsf(chi[row]);
    float cbest = 0.0f, ebest = -1.0f;
    #pragma unroll
    for (int kb = 0; kb < 3; ++kb) {
        float ck = amp * cosf(ph + 2.0943951023931953f * (float)kb) * expf(-achi * (float)kb);
        float ek = fabsf(ck) * nu;
        if (ek > ebest) { ebest = ek; cbest = ck; }
    }

    const float a = pa[0], gm = pgam[0];
    const float k0 = dk[0], k1 = dk[1], k2 = dk[2];
    for (int i = tid; i < 1024; i += 256) {
        float e = sErg[i];
        float l = (i > 0) ? sErg[i - 1] : 0.0f;
        float r = (i < 1023) ? sErg[i + 1] : 0.0f;
        float reac = e * (e - a) * (1.0f - e);
        float diff = k0 * l + k1 * e + k2 * r;
        float un = e + 0.1f * (reac + gm * diff);
        float s = un + cbest * Bb[i].x;
        uo[i] = s / (1.0f + expf(-s));
    }
}

// ---------------------------------------------------------------------------

extern "C" void kernel_launch(void* const* d_in, const int* in_sizes, int n_in,
                              void* d_out, int out_size, void* d_ws, size_t ws_size,
                              hipStream_t stream) {
    const float* c    = (const float*)d_in[0];
    const float* bw0  = (const float*)d_in[1];
    const float* sw0  = (const float*)d_in[2];
    const float* bw1  = (const float*)d_in[3];
    const float* sw1  = (const float*)d_in[4];
    const float* bw2  = (const float*)d_in[5];
    const float* sw2  = (const float*)d_in[6];
    const float* sg   = (const float*)d_in[7];
    const float* dk   = (const float*)d_in[8];
    const float* pa   = (const float*)d_in[9];
    const float* pgam = (const float*)d_in[10];
    const float* ptau = (const float*)d_in[11];
    const float* pvel = (const float*)d_in[12];
    const float* gp   = (const float*)d_in[13];
    const float* chi  = (const float*)d_in[14];

    const int B = 4096, NIN = 512, W = 1024, NOUT = 1024;
    const int KE0 = 19 * NIN, KE1 = 19 * W;
    const size_t MN = (size_t)B * W;
    const size_t BE = (size_t)W * KE1 * 2;      // Bexp bytes (39.85 MB)
    dim3 blk(256);
    dim3 gblk(512);

    // ---- pick (CH, S): 256-row m-tiles; {4096,4} -> gemm grid 4x16x4 = 256 = 1/CU ----
    struct Cand { int CH, S; };
    const Cand cands[] = {
        {4096, 4}, {4096, 3}, {2048, 4}, {2048, 3}, {1024, 4},
        {512, 4}, {256, 4}
    };
    int CH = 0, S = 1;
    for (const auto& cd : cands) {
        size_t need = BE + (size_t)cd.CH * KE1 * 2 + (size_t)cd.S * MN * 4;
        if (need <= ws_size) { CH = cd.CH; S = cd.S; break; }
    }

    if (CH > 0) {
        f16* Bexp = (f16*)d_ws;
        float* P  = (float*)((char*)d_ws + BE);                // S planes of M x N fp32
        f16* Aexp = (f16*)((char*)d_ws + BE + (size_t)S * MN * 4);

        // ceil-split Kc (multiple of 64 for BK=64; KE0/KE1 are 64-multiples)
        const int Kc0 = ((KE0 / 64 + S - 1) / S) * 64;
        const int Kc1 = ((KE1 / 64 + S - 1) / S) * 64;

        // ---- layer 0: KIN=512 ----
        prep_b<<<(W * NIN) / 256, blk, 0, stream>>>(bw0, sw0, Bexp, NIN, 9);
        for (int r0 = 0; r0 < B; r0 += CH) {
            expand_sum_a<<<(CH * NIN) / 256, blk, 0, stream>>>(
                c + (size_t)r0 * NIN, 0, 1, Aexp, NIN, 9);
            gemm_mfma<<<dim3(W / 256, CH / 256, S), gblk, 0, stream>>>(
                Aexp, Bexp, P + (size_t)r0 * W, KE0, Kc0, MN, W);
        }
        // ---- layer 1: KIN=1024 ----
        prep_b<<<(W * W) / 256, blk, 0, stream>>>(bw1, sw1, Bexp, W, 10);
        for (int r0 = 0; r0 < B; r0 += CH) {
            expand_sum_a<<<(CH * W) / 256, blk, 0, stream>>>(
                P + (size_t)r0 * W, MN, S, Aexp, W, 10);
            gemm_mfma<<<dim3(W / 256, CH / 256, S), gblk, 0, stream>>>(
                Aexp, Bexp, P + (size_t)r0 * W, KE1, Kc1, MN, W);
        }
        // ---- layer 2 ----
        prep_b<<<(NOUT * W) / 256, blk, 0, stream>>>(bw2, sw2, Bexp, W, 10);
        for (int r0 = 0; r0 < B; r0 += CH) {
            expand_sum_a<<<(CH * W) / 256, blk, 0, stream>>>(
                P + (size_t)r0 * W, MN, S, Aexp, W, 10);
            gemm_mfma<<<dim3(NOUT / 256, CH / 256, S), gblk, 0, stream>>>(
                Aexp, Bexp, P + (size_t)r0 * W, KE1, Kc1, MN, NOUT);
        }
        huxley_kernel<<<B, blk, 0, stream>>>(P, MN, S, (float*)d_out,
                                             sg, dk, pa, pgam, ptau, pvel, gp, chi);
    } else {
        // fallback: round-1 fp32 path (needs only 33.6 MB ws)
        float* fx0 = (float*)d_ws;
        float* fx1 = fx0 + (size_t)B * W;
        dim3 g0(W / 64, B / 64);
        kan_gemm<<<g0, blk, 0, stream>>>(c,   bw0, sw0, fx0, NIN, W);
        kan_gemm<<<g0, blk, 0, stream>>>(fx0, bw1, sw1, fx1, W,   W);
        dim3 g2(NOUT / 64, B / 64);
        kan_gemm<<<g2, blk, 0, stream>>>(fx1, bw2, sw2, (float*)d_out, W, NOUT);
        huxley_kernel<<<B, blk, 0, stream>>>((float*)d_out, 0, 1, (float*)d_out,
                                             sg, dk, pa, pgam, ptau, pvel, gp, chi);
    }
}

// Round 6
// 670.545 us; speedup vs baseline: 1.0416x; 1.0302x over previous
//
#include <hip/hip_runtime.h>
#include <math.h>

typedef _Float16 f16;
typedef _Float16 f16x8 __attribute__((ext_vector_type(8)));
typedef float f32x4 __attribute__((ext_vector_type(4)));

// ---------------------------------------------------------------------------
// expand_sum_a: x[b,i] = sum_{s<Sin} src[s*plane + b*KIN + i]  (Sin=1: raw input)
// -> Aexp (rows x KIN*19 fp16)
// planes per row: [0,8K): basis-hi | [8K,16K): basis-lo | xh | xh | xl
// ---------------------------------------------------------------------------
__global__ __launch_bounds__(256) void expand_sum_a(
    const float* __restrict__ src, size_t plane, int Sin,
    f16* __restrict__ Aexp, int KIN, int shift)
{
    int idx = blockIdx.x * 256 + threadIdx.x;
    int i = idx & (KIN - 1);
    int b = idx >> shift;
    float x = 0.0f;
    for (int s = 0; s < Sin; ++s) x += src[(size_t)s * plane + idx];

    float xs = (x + 2.2f) * 2.5f;
    float fj = floorf(xs);
    int jj = (int)fj;
    float t = xs - fj;
    float t2 = t * t, t3 = t2 * t;
    float omt = 1.0f - t;
    float p0 = omt * omt * omt * (1.0f / 6.0f);
    float p1 = (3.0f * t3 - 6.0f * t2 + 4.0f) * (1.0f / 6.0f);
    float p2 = (-3.0f * t3 + 3.0f * t2 + 3.0f * t + 1.0f) * (1.0f / 6.0f);
    float p3 = t3 * (1.0f / 6.0f);

    union { f16 h[8]; uint4 v; } hi, lo;
    bool inr = (jj >= 0 && jj <= 10);
    #pragma unroll
    for (int cc = 0; cc < 8; ++cc) {
        int d = cc - (jj - 3);
        float v = 0.0f;
        if (inr) {
            if (d == 0) v = p0; else if (d == 1) v = p1;
            else if (d == 2) v = p2; else if (d == 3) v = p3;
        }
        f16 h = (f16)v;
        hi.h[cc] = h;
        lo.h[cc] = (f16)(v - (float)h);
    }
    size_t KEXP = (size_t)KIN * 19;
    f16* row = Aexp + (size_t)b * KEXP;
    *(uint4*)(row + (size_t)i * 8) = hi.v;
    *(uint4*)(row + (size_t)KIN * 8 + (size_t)i * 8) = lo.v;
    f16 xh = (f16)x;
    f16 xl = (f16)(x - (float)xh);
    int K16 = KIN * 16;
    row[K16 + i] = xh;
    row[K16 + KIN + i] = xh;
    row[K16 + 2 * KIN + i] = xl;
}

// ---------------------------------------------------------------------------
// prep_b (round-3 verified): planes [qw x8][qw x8][wh][wl][wh]
// pairing with A: (bh+bl)*qw + xh*wh + xh*wl + xl*wh
// ---------------------------------------------------------------------------
__global__ __launch_bounds__(256) void prep_b(
    const float* __restrict__ BW, const float* __restrict__ SW,
    f16* __restrict__ Bexp, int KIN, int shift)
{
    int idx = blockIdx.x * 256 + threadIdx.x;
    int i = idx & (KIN - 1);
    int o = idx >> shift;
    const float* sp = SW + ((size_t)o * KIN + i) * 8;
    union { f16 h[8]; uint4 v; } pk;
    #pragma unroll
    for (int cc = 0; cc < 8; ++cc)
        pk.h[cc] = (f16)(rintf(sp[cc] * 32.0f) * 0.03125f);  // n/32, exact in fp16
    size_t KEXP = (size_t)KIN * 19;
    f16* row = Bexp + (size_t)o * KEXP;
    *(uint4*)(row + (size_t)i * 8) = pk.v;
    *(uint4*)(row + (size_t)KIN * 8 + (size_t)i * 8) = pk.v;
    float w = BW[(size_t)o * KIN + i];
    f16 wh = (f16)w;
    f16 wl = (f16)(w - (float)wh);
    int K16 = KIN * 16;
    row[K16 + i] = wh;
    row[K16 + KIN + i] = wl;
    row[K16 + 2 * KIN + i] = wh;
}

// ---------------------------------------------------------------------------
// gemm_mfma R10 (R3-verified best, 47.6% MfmaUtil): 256x256 block tile,
// 512 threads / 8 waves (2M x 4N), wave tile 128x64. 4-deep LDS ring of
// BK=32 K-tiles, prefetch distance 3, ONE barrier per K-tile:
//   tile t: [12 ds_read (af,bf,ag) + 4 gload_lds(t+3)] lgkm(4) 16 MFMA
//           lgkm(0) 16 MFMA  vmcnt(8|4|0)  s_barrier
// Sync ledger audited (see R3). XOR bank-swizzle verified; XCD-bijective
// block swizzle L = (b&7)*q + (b>>3) enumerated x-fastest.
// ---------------------------------------------------------------------------
__global__ __launch_bounds__(512, 2) void gemm_mfma(
    const f16* __restrict__ A, const f16* __restrict__ Bm,
    float* __restrict__ C, int Kfull, int Kc, size_t plane, int N)
{
    __shared__ __align__(16) f16 As[4][8192];   // [slot][256 rows x 32 k], 64B rows
    __shared__ __align__(16) f16 Bs[4][8192];   // [slot][256 rows x 32 k]

    const int tid = threadIdx.x;
    const int wave = tid >> 6, lane = tid & 63;

    const int nwg = gridDim.x * gridDim.y * gridDim.z;
    const int b = blockIdx.x + gridDim.x * (blockIdx.y + gridDim.y * blockIdx.z);
    const int q = nwg >> 3;
    const int L = (b & 7) * q + (b >> 3);
    const int lx = L % gridDim.x;
    const int rest = L / gridDim.x;
    const int ly = rest % gridDim.y;
    const int lz = rest / gridDim.y;

    const int m0 = ly * 256, n0 = lx * 256;
    const int kb = lz * Kc;
    int kcl = Kfull - kb; if (kcl > Kc) kcl = Kc;
    const int NT = kcl >> 5;

    const int kc_src = (lane & 3) ^ ((lane >> 3) & 3);
    const f16* gb[4];
    int isA_[4], coff[4];
    #pragma unroll
    for (int j = 0; j < 4; ++j) {
        int cch = wave * 4 + j;
        int a = (cch < 16);
        int c8 = a ? cch : (cch - 16);
        int row0 = (a ? m0 : n0) + c8 * 16 + (lane >> 2);
        gb[j] = (a ? A : Bm) + (size_t)row0 * Kfull + kb + kc_src * 8;
        isA_[j] = a;
        coff[j] = c8 * 512;
    }

    f32x4 acc[8][4];
    #pragma unroll
    for (int i = 0; i < 8; ++i)
        #pragma unroll
        for (int j = 0; j < 4; ++j)
            acc[i][j] = (f32x4){0.f, 0.f, 0.f, 0.f};

    #pragma unroll
    for (int s = 0; s < 3; ++s) {
        if (s < NT) {
            int k0 = s << 5;
            #pragma unroll
            for (int j = 0; j < 4; ++j) {
                f16* dp = isA_[j] ? &As[s][coff[j]] : &Bs[s][coff[j]];
                __builtin_amdgcn_global_load_lds(
                    (const __attribute__((address_space(1))) unsigned int*)(gb[j] + k0),
                    (__attribute__((address_space(3))) unsigned int*)dp, 16, 0, 0);
            }
        }
    }
    if (NT >= 3)      asm volatile("s_waitcnt vmcnt(8)" ::: "memory");
    else if (NT == 2) asm volatile("s_waitcnt vmcnt(4)" ::: "memory");
    else              asm volatile("s_waitcnt vmcnt(0)" ::: "memory");
    __builtin_amdgcn_s_barrier();
    asm volatile("" ::: "memory");

    const int lr = lane & 15;
    const int ko = (((lane >> 4) ^ ((lr >> 1) & 3)) & 3) * 8;
    const int wm = (wave & 1) * 128, wn = (wave >> 1) * 64;

    for (int t = 0; t < NT; ++t) {
        const int st = t & 3;
        const int ns = (t + 3) & 3;
        const bool pf = (t + 3 < NT);
        const int kn = (t + 3) << 5;
        const int rem = NT - 1 - t;

        f16x8 af[4], bf[4], ag[4];
        #pragma unroll
        for (int i = 0; i < 4; ++i)
            af[i] = *(const f16x8*)&As[st][(wm + i * 16 + lr) * 32 + ko];
        #pragma unroll
        for (int j = 0; j < 4; ++j)
            bf[j] = *(const f16x8*)&Bs[st][(wn + j * 16 + lr) * 32 + ko];
        if (pf) {
            #pragma unroll
            for (int j = 0; j < 2; ++j) {
                f16* dp = isA_[j] ? &As[ns][coff[j]] : &Bs[ns][coff[j]];
                __builtin_amdgcn_global_load_lds(
                    (const __attribute__((address_space(1))) unsigned int*)(gb[j] + kn),
                    (__attribute__((address_space(3))) unsigned int*)dp, 16, 0, 0);
            }
        }
        #pragma unroll
        for (int i = 0; i < 4; ++i)
            ag[i] = *(const f16x8*)&As[st][(wm + 64 + i * 16 + lr) * 32 + ko];
        if (pf) {
            #pragma unroll
            for (int j = 2; j < 4; ++j) {
                f16* dp = isA_[j] ? &As[ns][coff[j]] : &Bs[ns][coff[j]];
                __builtin_amdgcn_global_load_lds(
                    (const __attribute__((address_space(1))) unsigned int*)(gb[j] + kn),
                    (__attribute__((address_space(3))) unsigned int*)dp, 16, 0, 0);
            }
        }

        asm volatile("s_waitcnt lgkmcnt(4)" ::: "memory");
        __builtin_amdgcn_sched_barrier(0);
        __builtin_amdgcn_s_setprio(1);
        #pragma unroll
        for (int i = 0; i < 4; ++i)
            #pragma unroll
            for (int j = 0; j < 4; ++j)
                acc[i][j] = __builtin_amdgcn_mfma_f32_16x16x32_f16(af[i], bf[j], acc[i][j], 0, 0, 0);
        __builtin_amdgcn_s_setprio(0);

        asm volatile("s_waitcnt lgkmcnt(0)" ::: "memory");
        __builtin_amdgcn_sched_barrier(0);
        __builtin_amdgcn_s_setprio(1);
        #pragma unroll
        for (int i = 0; i < 4; ++i)
            #pragma unroll
            for (int j = 0; j < 4; ++j)
                acc[4 + i][j] = __builtin_amdgcn_mfma_f32_16x16x32_f16(ag[i], bf[j], acc[4 + i][j], 0, 0, 0);
        __builtin_amdgcn_s_setprio(0);

        if (rem >= 3)      asm volatile("s_waitcnt vmcnt(8)" ::: "memory");
        else if (rem == 2) asm volatile("s_waitcnt vmcnt(4)" ::: "memory");
        else if (rem == 1) asm volatile("s_waitcnt vmcnt(0)" ::: "memory");
        if (rem >= 1) {
            __builtin_amdgcn_sched_barrier(0);
            __builtin_amdgcn_s_barrier();
            asm volatile("" ::: "memory");
        }
    }

    // C/D layout: col=lane&15, row=(lane>>4)*4+reg  [m89-verified]
    float* Cp = C + (size_t)lz * plane;
    #pragma unroll
    for (int i = 0; i < 8; ++i) {
        int row = m0 + wm + i * 16 + (lane >> 4) * 4;
        #pragma unroll
        for (int j = 0; j < 4; ++j) {
            int col = n0 + wn + j * 16 + lr;
            #pragma unroll
            for (int rr = 0; rr < 4; ++rr)
                Cp[(size_t)(row + rr) * N + col] = acc[i][j][rr];
        }
    }
}

// ---------------------------------------------------------------------------
// Fallback fp32 GEMM (round-1 verified, used only if ws_size tiny)
// ---------------------------------------------------------------------------
__global__ __launch_bounds__(256) void kan_gemm(
    const float* __restrict__ X, const float* __restrict__ BW,
    const float* __restrict__ SW, float* __restrict__ Y, int KIN, int OUT)
{
    __shared__ __align__(16) float Asf[72][68];
    __shared__ __align__(16) float Bsf[72][68];
    const int tid = threadIdx.x;
    const int n0 = blockIdx.x * 64;
    const int m0 = blockIdx.y * 64;
    const int tx = tid & 15;
    const int ty = tid >> 4;
    float acc[4][4] = {};
    for (int k0 = 0; k0 < KIN; k0 += 8) {
        #pragma unroll
        for (int rep = 0; rep < 2; ++rep) {
            int idx = rep * 256 + tid;
            int r = idx >> 3, c = idx & 7;
            float x = X[(size_t)(m0 + r) * KIN + k0 + c];
            int bk = c * 9;
            Asf[bk][r] = x;
            #pragma unroll
            for (int z = 0; z < 8; ++z) Asf[bk + 1 + z][r] = 0.0f;
            float xs = (x + 2.2f) * 2.5f;
            float fj = floorf(xs);
            int j = (int)fj;
            if (j >= 0 && j <= 10) {
                float t = xs - fj;
                float t2 = t * t, t3 = t2 * t;
                float omt = 1.0f - t;
                float p0 = omt * omt * omt * (1.0f / 6.0f);
                float p1 = (3.0f * t3 - 6.0f * t2 + 4.0f) * (1.0f / 6.0f);
                float p2 = (-3.0f * t3 + 3.0f * t2 + 3.0f * t + 1.0f) * (1.0f / 6.0f);
                float p3 = t3 * (1.0f / 6.0f);
                if (j >= 3) Asf[bk + 1 + j - 3][r] = p0;
                if (j >= 2 && j <= 9) Asf[bk + 1 + j - 2][r] = p1;
                if (j >= 1 && j <= 8) Asf[bk + 1 + j - 1][r] = p2;
                if (j <= 7) Asf[bk + 1 + j][r] = p3;
            }
        }
        #pragma unroll
        for (int rep = 0; rep < 16; ++rep) {
            int idx = rep * 256 + tid;
            int ol = idx >> 6;
            int l = idx & 63;
            int i = l >> 3, cc = l & 7;
            float v = SW[((size_t)(n0 + ol) * KIN + k0 + i) * 8 + cc];
            Bsf[i * 9 + 1 + cc][ol] = rintf(v * 32.0f) * 0.03125f;
        }
        #pragma unroll
        for (int rep = 0; rep < 2; ++rep) {
            int idx = rep * 256 + tid;
            int ol = idx >> 3, cc = idx & 7;
            Bsf[cc * 9][ol] = BW[(size_t)(n0 + ol) * KIN + k0 + cc];
        }
        __syncthreads();
        #pragma unroll 8
        for (int kk = 0; kk < 72; ++kk) {
            float4 av = *(const float4*)&Asf[kk][ty * 4];
            float4 bv = *(const float4*)&Bsf[kk][tx * 4];
            acc[0][0] += av.x * bv.x; acc[0][1] += av.x * bv.y; acc[0][2] += av.x * bv.z; acc[0][3] += av.x * bv.w;
            acc[1][0] += av.y * bv.x; acc[1][1] += av.y * bv.y; acc[1][2] += av.y * bv.z; acc[1][3] += av.y * bv.w;
            acc[2][0] += av.z * bv.x; acc[2][1] += av.z * bv.y; acc[2][2] += av.z * bv.z; acc[2][3] += av.z * bv.w;
            acc[3][0] += av.w * bv.x; acc[3][1] += av.w * bv.y; acc[3][2] += av.w * bv.z; acc[3][3] += av.w * bv.w;
        }
        __syncthreads();
    }
    #pragma unroll
    for (int i = 0; i < 4; ++i) {
        float4 o = make_float4(acc[i][0], acc[i][1], acc[i][2], acc[i][3]);
        *(float4*)&Y[(size_t)(m0 + ty * 4 + i) * OUT + n0 + tx * 4] = o;
    }
}

// ---------------------------------------------------------------------------
// huxley_rd R13: PAIRED rows. Block handles rows (2b, 2b+1) packed as
// z = u1 + i*u2. All spectral multipliers are linear + row-separable:
//   gate g(m): real symmetric -> ifft(g.Z) = u_erg1 + i*u_erg2   (exact)
//   phase H(k): conj-symmetric (k<=512: e^{-i*2pi*k*v/N}, mirror conj)
//     -> ifft(H.(1-g).Z) = u_ne_shift1 + i*u_ne_shift2           (exact)
//   bin 512: numpy irfft keeps only Re per row -> use cos-only multiplier
//     (omg*cos(ang)*Z[512]) which keeps each row's spectrum conj-symmetric.
// Per-row |spectrum| (sAbs) needs separation: F1 = .5(Z[k]+conj(Z[N-k])),
//   F2 = -.5i(Z[k]-conj(Z[N-k])) -- one extra LDS read + brev per bin.
// Reductions float2 (both rows per pass). 3 complex FFTs per TWO rows.
// ---------------------------------------------------------------------------
__device__ __forceinline__ float2 block_reduce_sum2(float2 v, float2* red, int tid) {
    red[tid] = v; __syncthreads();
    #pragma unroll
    for (int s = 128; s > 0; s >>= 1) {
        if (tid < s) {
            red[tid].x += red[tid + s].x;
            red[tid].y += red[tid + s].y;
        }
        __syncthreads();
    }
    float2 r = red[0]; __syncthreads();
    return r;
}
__device__ __forceinline__ float2 block_reduce_min2(float2 v, float2* red, int tid) {
    red[tid] = v; __syncthreads();
    #pragma unroll
    for (int s = 128; s > 0; s >>= 1) {
        if (tid < s) {
            red[tid].x = fminf(red[tid].x, red[tid + s].x);
            red[tid].y = fminf(red[tid].y, red[tid + s].y);
        }
        __syncthreads();
    }
    float2 r = red[0]; __syncthreads();
    return r;
}

__device__ void fft1024(float2* X, const float2* tw, int tid, bool inverse) {
    if (!inverse) {
        for (int sh = 9; sh >= 0; --sh) {
            int h = 1 << sh;
            #pragma unroll
            for (int q = 0; q < 2; ++q) {
                int b = tid + q * 256;
                int g = b >> sh, j = b & (h - 1);
                int i0 = (g << (sh + 1)) + j, i1 = i0 + h;
                float2 u = X[i0], v = X[i1];
                float dx = u.x - v.x, dy = u.y - v.y;
                X[i0] = make_float2(u.x + v.x, u.y + v.y);
                float2 w = tw[j << (9 - sh)];
                X[i1] = make_float2(dx * w.x + dy * w.y, dy * w.x - dx * w.y);
            }
            __syncthreads();
        }
    } else {
        for (int sh = 0; sh <= 9; ++sh) {
            int h = 1 << sh;
            #pragma unroll
            for (int q = 0; q < 2; ++q) {
                int b = tid + q * 256;
                int g = b >> sh, j = b & (h - 1);
                int i0 = (g << (sh + 1)) + j, i1 = i0 + h;
                float2 u = X[i0], v = X[i1];
                float2 w = tw[j << (9 - sh)];
                float tx2 = v.x * w.x - v.y * w.y;
                float ty2 = v.x * w.y + v.y * w.x;
                X[i0] = make_float2(u.x + tx2, u.y + ty2);
                X[i1] = make_float2(u.x - tx2, u.y - ty2);
            }
            __syncthreads();
        }
    }
}

__global__ __launch_bounds__(256) void huxley_kernel(
    const float* __restrict__ Pin, size_t plane, int S,
    float* __restrict__ dst,
    const float* __restrict__ sg, const float* __restrict__ dk,
    const float* __restrict__ pa, const float* __restrict__ pgam,
    const float* __restrict__ ptau, const float* __restrict__ pvel,
    const float* __restrict__ gp, const float* __restrict__ chi)
{
    __shared__ float2 A[1024];
    __shared__ float2 Bb[1024];
    __shared__ float2 sErg[1024];
    __shared__ float sAbs1[516];
    __shared__ float sAbs2[516];
    __shared__ float2 tw[512];
    __shared__ float2 red2[256];
    __shared__ float sG[516];

    const int tid = threadIdx.x;
    const int r0 = blockIdx.x * 2;
    const float* pin0 = Pin + (size_t)r0 * 1024;
    const float* pin1 = Pin + (size_t)(r0 + 1) * 1024;
    float* uo0 = dst + (size_t)r0 * 1024;
    float* uo1 = dst + (size_t)(r0 + 1) * 1024;

    for (int m = tid; m < 512; m += 256) {
        float s, c;
        sincosf(6.283185307179586f * (float)m * (1.0f / 1024.0f), &s, &c);
        tw[m] = make_float2(c, s);
    }
    for (int k = tid; k < 513; k += 256)
        sG[k] = 1.0f / (1.0f + expf(-sg[k]));
    for (int i = tid; i < 1024; i += 256) {
        float s0 = 0.0f, s1 = 0.0f;
        for (int ss = 0; ss < S; ++ss) {
            s0 += pin0[(size_t)ss * plane + i];
            s1 += pin1[(size_t)ss * plane + i];
        }
        A[i] = make_float2(s0, s1);   // packed: row1 + i*row2
    }
    __syncthreads();

    fft1024(A, tw, tid, false);       // A = Z (bit-reversed order)

    // ---- gated (erg) path: multiplier g(m) real symmetric -> packed exact ----
    for (int p = tid; p < 1024; p += 256) {
        int k = (int)(__brev((unsigned)p) >> 22);
        int m = (k <= 512) ? k : 1024 - k;
        float g = sG[m] * (1.0f / 1024.0f);
        Bb[p] = make_float2(A[p].x * g, A[p].y * g);
    }
    __syncthreads();
    fft1024(Bb, tw, tid, true);
    for (int i = tid; i < 1024; i += 256) sErg[i] = Bb[i];   // .x=row1, .y=row2
    __syncthreads();

    // ---- non-erg path: (1-g), phase shift, per-row magnitudes ----
    const float vv = pvel[0];
    for (int p = tid; p < 1024; p += 256) {
        int k = (int)(__brev((unsigned)p) >> 22);
        int m = (k <= 512) ? k : 1024 - k;
        float omg = 1.0f - sG[m];
        float2 z = A[p];
        float nx = z.x * omg, ny = z.y * omg;
        float ang = (k <= 512)
            ? (-6.283185307179586f * vv * (float)k * (1.0f / 1024.0f))
            : (6.283185307179586f * vv * (float)(1024 - k) * (1.0f / 1024.0f));
        float sn, cs;
        sincosf(ang, &sn, &cs);
        float yx, yy;
        if (k == 512) {
            // keep each row's effective bin-512 real (numpy irfft keeps Re only)
            yx = nx * cs;
            yy = ny * cs;
            sAbs1[512] = fabsf(nx * cs);
            sAbs2[512] = fabsf(ny * cs);
        } else {
            yx = nx * cs - ny * sn;
            yy = nx * sn + ny * cs;
            if (k < 512) {
                int p2 = (int)(__brev((unsigned)((1024 - k) & 1023)) >> 22);
                float2 z2 = A[p2];
                // F1 = .5(Z[k]+conj(Z[N-k])), F2 = -.5i(Z[k]-conj(Z[N-k]))
                float f1x = 0.5f * (z.x + z2.x), f1y = 0.5f * (z.y - z2.y);
                float f2x = 0.5f * (z.y + z2.y), f2y = 0.5f * (z2.x - z.x);
                sAbs1[k] = omg * sqrtf(f1x * f1x + f1y * f1y);
                sAbs2[k] = omg * sqrtf(f2x * f2x + f2y * f2y);
            }
        }
        Bb[p] = make_float2(yx * (1.0f / 1024.0f), yy * (1.0f / 1024.0f));
    }
    __syncthreads();
    fft1024(Bb, tw, tid, true);       // Bb = u_ne_shift1 + i*u_ne_shift2

    // ---- reductions (both rows per pass) ----
    float2 loc = make_float2(0.0f, 0.0f);
    for (int i = tid; i < 1024; i += 256) {
        loc.x += Bb[i].x * Bb[i].x;
        loc.y += Bb[i].y * Bb[i].y;
    }
    float2 trc = block_reduce_sum2(loc, red2, tid);

    loc = make_float2(0.0f, 0.0f);
    for (int k = tid; k < 513; k += 256) { loc.x += sAbs1[k]; loc.y += sAbs2[k]; }
    float2 msum = block_reduce_sum2(loc, red2, tid);
    float2 mean = make_float2(msum.x * (1.0f / 513.0f), msum.y * (1.0f / 513.0f));

    loc = make_float2(0.0f, 0.0f);
    for (int k = tid; k < 513; k += 256) {
        float d1 = sAbs1[k] - mean.x;
        float d2 = sAbs2[k] - mean.y;
        loc.x += d1 * d1; loc.y += d2 * d2;
    }
    float2 varsum = block_reduce_sum2(loc, red2, tid);

    loc = make_float2(3.4e38f, 3.4e38f);
    for (int k = tid; k < 513; k += 256) {
        loc.x = fminf(loc.x, sAbs1[k]);
        loc.y = fminf(loc.y, sAbs2[k]);
    }
    float2 lmin = block_reduce_min2(loc, red2, tid);

    // ---- per-row scalars ----
    const float tauv = ptau[0];
    float trcv[2]  = { trc.x, trc.y };
    float varv[2]  = { varsum.x, varsum.y };
    float lminv[2] = { lmin.x, lmin.y };
    float gpv[2]   = { gp[r0], gp[r0 + 1] };
    float chv[2]   = { chi[r0], chi[r0 + 1] };
    float cb[2];
    #pragma unroll
    for (int rr = 0; rr < 2; ++rr) {
        float det_pas = varv[rr] * (1.0f / 512.0f) + 1e-6f;
        float sd = sqrtf(det_pas);
        float denom = 2.0f * sd * sd * sd + 1e-8f;
        float c3 = (3.0f * gpv[rr] - trcv[rr] / tauv) / denom;
        c3 = fminf(fmaxf(c3, -0.999f), 0.999f);
        float ph = acosf(c3) * (1.0f / 3.0f);
        float amp = 2.0f * sqrtf(lminv[rr] * (1.0f / 3.0f) + 1e-8f);
        float nu = sqrtf(trcv[rr]);
        float achi = fabsf(chv[rr]);
        float cbest = 0.0f, ebest = -1.0f;
        #pragma unroll
        for (int kb = 0; kb < 3; ++kb) {
            float ck = amp * cosf(ph + 2.0943951023931953f * (float)kb) * expf(-achi * (float)kb);
            float ek = fabsf(ck) * nu;
            if (ek > ebest) { ebest = ek; cbest = ck; }
        }
        cb[rr] = cbest;
    }

    // ---- final elementwise (both rows) ----
    const float a = pa[0], gm = pgam[0];
    const float k0 = dk[0], k1 = dk[1], k2 = dk[2];
    for (int i = tid; i < 1024; i += 256) {
        float2 e = sErg[i];
        float2 l = (i > 0) ? sErg[i - 1] : make_float2(0.0f, 0.0f);
        float2 r = (i < 1023) ? sErg[i + 1] : make_float2(0.0f, 0.0f);
        // row 1
        float reac1 = e.x * (e.x - a) * (1.0f - e.x);
        float diff1 = k0 * l.x + k1 * e.x + k2 * r.x;
        float un1 = e.x + 0.1f * (reac1 + gm * diff1);
        float s1 = un1 + cb[0] * Bb[i].x;
        uo0[i] = s1 / (1.0f + expf(-s1));
        // row 2
        float reac2 = e.y * (e.y - a) * (1.0f - e.y);
        float diff2 = k0 * l.y + k1 * e.y + k2 * r.y;
        float un2 = e.y + 0.1f * (reac2 + gm * diff2);
        float s2 = un2 + cb[1] * Bb[i].y;
        uo1[i] = s2 / (1.0f + expf(-s2));
    }
}

// ---------------------------------------------------------------------------

extern "C" void kernel_launch(void* const* d_in, const int* in_sizes, int n_in,
                              void* d_out, int out_size, void* d_ws, size_t ws_size,
                              hipStream_t stream) {
    const float* c    = (const float*)d_in[0];
    const float* bw0  = (const float*)d_in[1];
    const float* sw0  = (const float*)d_in[2];
    const float* bw1  = (const float*)d_in[3];
    const float* sw1  = (const float*)d_in[4];
    const float* bw2  = (const float*)d_in[5];
    const float* sw2  = (const float*)d_in[6];
    const float* sg   = (const float*)d_in[7];
    const float* dk   = (const float*)d_in[8];
    const float* pa   = (const float*)d_in[9];
    const float* pgam = (const float*)d_in[10];
    const float* ptau = (const float*)d_in[11];
    const float* pvel = (const float*)d_in[12];
    const float* gp   = (const float*)d_in[13];
    const float* chi  = (const float*)d_in[14];

    const int B = 4096, NIN = 512, W = 1024, NOUT = 1024;
    const int KE0 = 19 * NIN, KE1 = 19 * W;
    const size_t MN = (size_t)B * W;
    const size_t BE = (size_t)W * KE1 * 2;      // Bexp bytes (39.85 MB)
    dim3 blk(256);
    dim3 gblk(512);

    // ---- pick (CH, S): 256-row m-tiles; {4096,4} -> gemm grid 4x16x4 = 256 = 1/CU ----
    struct Cand { int CH, S; };
    const Cand cands[] = {
        {4096, 4}, {4096, 3}, {2048, 4}, {2048, 3}, {1024, 4},
        {512, 4}, {256, 4}
    };
    int CH = 0, S = 1;
    for (const auto& cd : cands) {
        size_t need = BE + (size_t)cd.CH * KE1 * 2 + (size_t)cd.S * MN * 4;
        if (need <= ws_size) { CH = cd.CH; S = cd.S; break; }
    }

    if (CH > 0) {
        f16* Bexp = (f16*)d_ws;
        float* P  = (float*)((char*)d_ws + BE);                // S planes of M x N fp32
        f16* Aexp = (f16*)((char*)d_ws + BE + (size_t)S * MN * 4);

        // ceil-split Kc (multiple of 32); kernel clamps last split
        const int Kc0 = ((KE0 / 32 + S - 1) / S) * 32;
        const int Kc1 = ((KE1 / 32 + S - 1) / S) * 32;

        // ---- layer 0: KIN=512 ----
        prep_b<<<(W * NIN) / 256, blk, 0, stream>>>(bw0, sw0, Bexp, NIN, 9);
        for (int r0 = 0; r0 < B; r0 += CH) {
            expand_sum_a<<<(CH * NIN) / 256, blk, 0, stream>>>(
                c + (size_t)r0 * NIN, 0, 1, Aexp, NIN, 9);
            gemm_mfma<<<dim3(W / 256, CH / 256, S), gblk, 0, stream>>>(
                Aexp, Bexp, P + (size_t)r0 * W, KE0, Kc0, MN, W);
        }
        // ---- layer 1: KIN=1024 ----
        prep_b<<<(W * W) / 256, blk, 0, stream>>>(bw1, sw1, Bexp, W, 10);
        for (int r0 = 0; r0 < B; r0 += CH) {
            expand_sum_a<<<(CH * W) / 256, blk, 0, stream>>>(
                P + (size_t)r0 * W, MN, S, Aexp, W, 10);
            gemm_mfma<<<dim3(W / 256, CH / 256, S), gblk, 0, stream>>>(
                Aexp, Bexp, P + (size_t)r0 * W, KE1, Kc1, MN, W);
        }
        // ---- layer 2 ----
        prep_b<<<(NOUT * W) / 256, blk, 0, stream>>>(bw2, sw2, Bexp, W, 10);
        for (int r0 = 0; r0 < B; r0 += CH) {
            expand_sum_a<<<(CH * W) / 256, blk, 0, stream>>>(
                P + (size_t)r0 * W, MN, S, Aexp, W, 10);
            gemm_mfma<<<dim3(NOUT / 256, CH / 256, S), gblk, 0, stream>>>(
                Aexp, Bexp, P + (size_t)r0 * W, KE1, Kc1, MN, NOUT);
        }
        huxley_kernel<<<B / 2, blk, 0, stream>>>(P, MN, S, (float*)d_out,
                                                 sg, dk, pa, pgam, ptau, pvel, gp, chi);
    } else {
        // fallback: round-1 fp32 path (needs only 33.6 MB ws)
        float* fx0 = (float*)d_ws;
        float* fx1 = fx0 + (size_t)B * W;
        dim3 g0(W / 64, B / 64);
        kan_gemm<<<g0, blk, 0, stream>>>(c,   bw0, sw0, fx0, NIN, W);
        kan_gemm<<<g0, blk, 0, stream>>>(fx0, bw1, sw1, fx1, W,   W);
        dim3 g2(NOUT / 64, B / 64);
        kan_gemm<<<g2, blk, 0, stream>>>(fx1, bw2, sw2, (float*)d_out, W, NOUT);
        huxley_kernel<<<B / 2, blk, 0, stream>>>((float*)d_out, 0, 1, (float*)d_out,
                                                 sg, dk, pa, pgam, ptau, pvel, gp, chi);
    }
}

// Round 7
// 664.486 us; speedup vs baseline: 1.0511x; 1.0091x over previous
//
#include <hip/hip_runtime.h>
#include <math.h>

typedef _Float16 f16;
typedef _Float16 f16x8 __attribute__((ext_vector_type(8)));
typedef float f32x4 __attribute__((ext_vector_type(4)));

// ---------------------------------------------------------------------------
// expand_sum_a: x[b,i] = sum_{s<Sin} src[s*plane + b*KIN + i]  (Sin=1: raw input)
// -> Aexp (rows x KIN*19 fp16)
// planes per row: [0,8K): basis-hi | [8K,16K): basis-lo | xh | xh | xl
// ---------------------------------------------------------------------------
__global__ __launch_bounds__(256) void expand_sum_a(
    const float* __restrict__ src, size_t plane, int Sin,
    f16* __restrict__ Aexp, int KIN, int shift)
{
    int idx = blockIdx.x * 256 + threadIdx.x;
    int i = idx & (KIN - 1);
    int b = idx >> shift;
    float x = 0.0f;
    for (int s = 0; s < Sin; ++s) x += src[(size_t)s * plane + idx];

    float xs = (x + 2.2f) * 2.5f;
    float fj = floorf(xs);
    int jj = (int)fj;
    float t = xs - fj;
    float t2 = t * t, t3 = t2 * t;
    float omt = 1.0f - t;
    float p0 = omt * omt * omt * (1.0f / 6.0f);
    float p1 = (3.0f * t3 - 6.0f * t2 + 4.0f) * (1.0f / 6.0f);
    float p2 = (-3.0f * t3 + 3.0f * t2 + 3.0f * t + 1.0f) * (1.0f / 6.0f);
    float p3 = t3 * (1.0f / 6.0f);

    union { f16 h[8]; uint4 v; } hi, lo;
    bool inr = (jj >= 0 && jj <= 10);
    #pragma unroll
    for (int cc = 0; cc < 8; ++cc) {
        int d = cc - (jj - 3);
        float v = 0.0f;
        if (inr) {
            if (d == 0) v = p0; else if (d == 1) v = p1;
            else if (d == 2) v = p2; else if (d == 3) v = p3;
        }
        f16 h = (f16)v;
        hi.h[cc] = h;
        lo.h[cc] = (f16)(v - (float)h);
    }
    size_t KEXP = (size_t)KIN * 19;
    f16* row = Aexp + (size_t)b * KEXP;
    *(uint4*)(row + (size_t)i * 8) = hi.v;
    *(uint4*)(row + (size_t)KIN * 8 + (size_t)i * 8) = lo.v;
    f16 xh = (f16)x;
    f16 xl = (f16)(x - (float)xh);
    int K16 = KIN * 16;
    row[K16 + i] = xh;
    row[K16 + KIN + i] = xh;
    row[K16 + 2 * KIN + i] = xl;
}

// ---------------------------------------------------------------------------
// prep_b (round-3 verified): planes [qw x8][qw x8][wh][wl][wh]
// pairing with A: (bh+bl)*qw + xh*wh + xh*wl + xl*wh
// ---------------------------------------------------------------------------
__global__ __launch_bounds__(256) void prep_b(
    const float* __restrict__ BW, const float* __restrict__ SW,
    f16* __restrict__ Bexp, int KIN, int shift)
{
    int idx = blockIdx.x * 256 + threadIdx.x;
    int i = idx & (KIN - 1);
    int o = idx >> shift;
    const float* sp = SW + ((size_t)o * KIN + i) * 8;
    union { f16 h[8]; uint4 v; } pk;
    #pragma unroll
    for (int cc = 0; cc < 8; ++cc)
        pk.h[cc] = (f16)(rintf(sp[cc] * 32.0f) * 0.03125f);  // n/32, exact in fp16
    size_t KEXP = (size_t)KIN * 19;
    f16* row = Bexp + (size_t)o * KEXP;
    *(uint4*)(row + (size_t)i * 8) = pk.v;
    *(uint4*)(row + (size_t)KIN * 8 + (size_t)i * 8) = pk.v;
    float w = BW[(size_t)o * KIN + i];
    f16 wh = (f16)w;
    f16 wl = (f16)(w - (float)wh);
    int K16 = KIN * 16;
    row[K16 + i] = wh;
    row[K16 + KIN + i] = wl;
    row[K16 + 2 * KIN + i] = wh;
}

// ---------------------------------------------------------------------------
// gemm_mfma (ring-4, R3-verified, 47.6% MfmaUtil): used when S<=4 (1 blk/CU).
// 256x256 tile, 512 thr / 8 waves (2Mx4N), wave tile 128x64, 4-slot BK=32
// ring, prefetch 3, ONE barrier/K-tile, counted vmcnt 8/4/0 + lgkm 4/0.
// XOR bank-swizzle + XCD-bijective block swizzle (see R3 ledger).
// ---------------------------------------------------------------------------
__global__ __launch_bounds__(512, 2) void gemm_mfma(
    const f16* __restrict__ A, const f16* __restrict__ Bm,
    float* __restrict__ C, int Kfull, int Kc, size_t plane, int N)
{
    __shared__ __align__(16) f16 As[4][8192];
    __shared__ __align__(16) f16 Bs[4][8192];

    const int tid = threadIdx.x;
    const int wave = tid >> 6, lane = tid & 63;

    const int nwg = gridDim.x * gridDim.y * gridDim.z;
    const int b = blockIdx.x + gridDim.x * (blockIdx.y + gridDim.y * blockIdx.z);
    const int q = nwg >> 3;
    const int L = (b & 7) * q + (b >> 3);
    const int lx = L % gridDim.x;
    const int rest = L / gridDim.x;
    const int ly = rest % gridDim.y;
    const int lz = rest / gridDim.y;

    const int m0 = ly * 256, n0 = lx * 256;
    const int kb = lz * Kc;
    int kcl = Kfull - kb; if (kcl > Kc) kcl = Kc;
    const int NT = kcl >> 5;

    const int kc_src = (lane & 3) ^ ((lane >> 3) & 3);
    const f16* gb[4];
    int isA_[4], coff[4];
    #pragma unroll
    for (int j = 0; j < 4; ++j) {
        int cch = wave * 4 + j;
        int a = (cch < 16);
        int c8 = a ? cch : (cch - 16);
        int row0 = (a ? m0 : n0) + c8 * 16 + (lane >> 2);
        gb[j] = (a ? A : Bm) + (size_t)row0 * Kfull + kb + kc_src * 8;
        isA_[j] = a;
        coff[j] = c8 * 512;
    }

    f32x4 acc[8][4];
    #pragma unroll
    for (int i = 0; i < 8; ++i)
        #pragma unroll
        for (int j = 0; j < 4; ++j)
            acc[i][j] = (f32x4){0.f, 0.f, 0.f, 0.f};

    #pragma unroll
    for (int s = 0; s < 3; ++s) {
        if (s < NT) {
            int k0 = s << 5;
            #pragma unroll
            for (int j = 0; j < 4; ++j) {
                f16* dp = isA_[j] ? &As[s][coff[j]] : &Bs[s][coff[j]];
                __builtin_amdgcn_global_load_lds(
                    (const __attribute__((address_space(1))) unsigned int*)(gb[j] + k0),
                    (__attribute__((address_space(3))) unsigned int*)dp, 16, 0, 0);
            }
        }
    }
    if (NT >= 3)      asm volatile("s_waitcnt vmcnt(8)" ::: "memory");
    else if (NT == 2) asm volatile("s_waitcnt vmcnt(4)" ::: "memory");
    else              asm volatile("s_waitcnt vmcnt(0)" ::: "memory");
    __builtin_amdgcn_s_barrier();
    asm volatile("" ::: "memory");

    const int lr = lane & 15;
    const int ko = (((lane >> 4) ^ ((lr >> 1) & 3)) & 3) * 8;
    const int wm = (wave & 1) * 128, wn = (wave >> 1) * 64;

    for (int t = 0; t < NT; ++t) {
        const int st = t & 3;
        const int ns = (t + 3) & 3;
        const bool pf = (t + 3 < NT);
        const int kn = (t + 3) << 5;
        const int rem = NT - 1 - t;

        f16x8 af[4], bf[4], ag[4];
        #pragma unroll
        for (int i = 0; i < 4; ++i)
            af[i] = *(const f16x8*)&As[st][(wm + i * 16 + lr) * 32 + ko];
        #pragma unroll
        for (int j = 0; j < 4; ++j)
            bf[j] = *(const f16x8*)&Bs[st][(wn + j * 16 + lr) * 32 + ko];
        if (pf) {
            #pragma unroll
            for (int j = 0; j < 2; ++j) {
                f16* dp = isA_[j] ? &As[ns][coff[j]] : &Bs[ns][coff[j]];
                __builtin_amdgcn_global_load_lds(
                    (const __attribute__((address_space(1))) unsigned int*)(gb[j] + kn),
                    (__attribute__((address_space(3))) unsigned int*)dp, 16, 0, 0);
            }
        }
        #pragma unroll
        for (int i = 0; i < 4; ++i)
            ag[i] = *(const f16x8*)&As[st][(wm + 64 + i * 16 + lr) * 32 + ko];
        if (pf) {
            #pragma unroll
            for (int j = 2; j < 4; ++j) {
                f16* dp = isA_[j] ? &As[ns][coff[j]] : &Bs[ns][coff[j]];
                __builtin_amdgcn_global_load_lds(
                    (const __attribute__((address_space(1))) unsigned int*)(gb[j] + kn),
                    (__attribute__((address_space(3))) unsigned int*)dp, 16, 0, 0);
            }
        }

        asm volatile("s_waitcnt lgkmcnt(4)" ::: "memory");
        __builtin_amdgcn_sched_barrier(0);
        __builtin_amdgcn_s_setprio(1);
        #pragma unroll
        for (int i = 0; i < 4; ++i)
            #pragma unroll
            for (int j = 0; j < 4; ++j)
                acc[i][j] = __builtin_amdgcn_mfma_f32_16x16x32_f16(af[i], bf[j], acc[i][j], 0, 0, 0);
        __builtin_amdgcn_s_setprio(0);

        asm volatile("s_waitcnt lgkmcnt(0)" ::: "memory");
        __builtin_amdgcn_sched_barrier(0);
        __builtin_amdgcn_s_setprio(1);
        #pragma unroll
        for (int i = 0; i < 4; ++i)
            #pragma unroll
            for (int j = 0; j < 4; ++j)
                acc[4 + i][j] = __builtin_amdgcn_mfma_f32_16x16x32_f16(ag[i], bf[j], acc[4 + i][j], 0, 0, 0);
        __builtin_amdgcn_s_setprio(0);

        if (rem >= 3)      asm volatile("s_waitcnt vmcnt(8)" ::: "memory");
        else if (rem == 2) asm volatile("s_waitcnt vmcnt(4)" ::: "memory");
        else if (rem == 1) asm volatile("s_waitcnt vmcnt(0)" ::: "memory");
        if (rem >= 1) {
            __builtin_amdgcn_sched_barrier(0);
            __builtin_amdgcn_s_barrier();
            asm volatile("" ::: "memory");
        }
    }

    float* Cp = C + (size_t)lz * plane;
    #pragma unroll
    for (int i = 0; i < 8; ++i) {
        int row = m0 + wm + i * 16 + (lane >> 4) * 4;
        #pragma unroll
        for (int j = 0; j < 4; ++j) {
            int col = n0 + wn + j * 16 + lr;
            #pragma unroll
            for (int rr = 0; rr < 4; ++rr)
                Cp[(size_t)(row + rr) * N + col] = acc[i][j][rr];
        }
    }
}

// ---------------------------------------------------------------------------
// gemm_mfma2 R14: ring-2 variant, LDS 64KB -> 2 blocks/CU. Used when S==8
// (grid 512 = 2 blocks/CU). Same 256x256 tile / wave layout / swizzles as
// ring-4; prefetch distance 1; full vmcnt(0) drain per tile is hidden by
// the co-resident block (cross-block TLP -- blocks never share barriers).
// Sync ledger: fill -> gloads(t) issued at t-1, drained by vmcnt(0) before
// barrier(end t-1) in every wave. overwrite -> gloads(t+1) target slot st^1
// (held tile t-1); its readers finished (own lgkm(0) at t-1) before passing
// barrier(end t-1); gloads issue after it. Edge NT=1: no loop gloads/barrier.
// __launch_bounds__(512,4): 16 waves/CU -> VGPR cap 128 (current use ~100).
// ---------------------------------------------------------------------------
__global__ __launch_bounds__(512, 4) void gemm_mfma2(
    const f16* __restrict__ A, const f16* __restrict__ Bm,
    float* __restrict__ C, int Kfull, int Kc, size_t plane, int N)
{
    __shared__ __align__(16) f16 As[2][8192];
    __shared__ __align__(16) f16 Bs[2][8192];

    const int tid = threadIdx.x;
    const int wave = tid >> 6, lane = tid & 63;

    const int nwg = gridDim.x * gridDim.y * gridDim.z;
    const int b = blockIdx.x + gridDim.x * (blockIdx.y + gridDim.y * blockIdx.z);
    const int q = nwg >> 3;
    const int L = (b & 7) * q + (b >> 3);
    const int lx = L % gridDim.x;
    const int rest = L / gridDim.x;
    const int ly = rest % gridDim.y;
    const int lz = rest / gridDim.y;

    const int m0 = ly * 256, n0 = lx * 256;
    const int kb = lz * Kc;
    int kcl = Kfull - kb; if (kcl > Kc) kcl = Kc;
    const int NT = kcl >> 5;

    const int kc_src = (lane & 3) ^ ((lane >> 3) & 3);
    const f16* gb[4];
    int isA_[4], coff[4];
    #pragma unroll
    for (int j = 0; j < 4; ++j) {
        int cch = wave * 4 + j;
        int a = (cch < 16);
        int c8 = a ? cch : (cch - 16);
        int row0 = (a ? m0 : n0) + c8 * 16 + (lane >> 2);
        gb[j] = (a ? A : Bm) + (size_t)row0 * Kfull + kb + kc_src * 8;
        isA_[j] = a;
        coff[j] = c8 * 512;
    }

    f32x4 acc[8][4];
    #pragma unroll
    for (int i = 0; i < 8; ++i)
        #pragma unroll
        for (int j = 0; j < 4; ++j)
            acc[i][j] = (f32x4){0.f, 0.f, 0.f, 0.f};

    // prologue: tile 0 -> slot 0
    #pragma unroll
    for (int j = 0; j < 4; ++j) {
        f16* dp = isA_[j] ? &As[0][coff[j]] : &Bs[0][coff[j]];
        __builtin_amdgcn_global_load_lds(
            (const __attribute__((address_space(1))) unsigned int*)(gb[j]),
            (__attribute__((address_space(3))) unsigned int*)dp, 16, 0, 0);
    }
    asm volatile("s_waitcnt vmcnt(0)" ::: "memory");
    __builtin_amdgcn_s_barrier();
    asm volatile("" ::: "memory");

    const int lr = lane & 15;
    const int ko = (((lane >> 4) ^ ((lr >> 1) & 3)) & 3) * 8;
    const int wm = (wave & 1) * 128, wn = (wave >> 1) * 64;

    for (int t = 0; t < NT; ++t) {
        const int st = t & 1;
        const int ns = st ^ 1;
        const bool pf = (t + 1 < NT);
        const int kn = (t + 1) << 5;

        f16x8 af[4], bf[4], ag[4];
        #pragma unroll
        for (int i = 0; i < 4; ++i)
            af[i] = *(const f16x8*)&As[st][(wm + i * 16 + lr) * 32 + ko];
        #pragma unroll
        for (int j = 0; j < 4; ++j)
            bf[j] = *(const f16x8*)&Bs[st][(wn + j * 16 + lr) * 32 + ko];
        if (pf) {
            #pragma unroll
            for (int j = 0; j < 2; ++j) {
                f16* dp = isA_[j] ? &As[ns][coff[j]] : &Bs[ns][coff[j]];
                __builtin_amdgcn_global_load_lds(
                    (const __attribute__((address_space(1))) unsigned int*)(gb[j] + kn),
                    (__attribute__((address_space(3))) unsigned int*)dp, 16, 0, 0);
            }
        }
        #pragma unroll
        for (int i = 0; i < 4; ++i)
            ag[i] = *(const f16x8*)&As[st][(wm + 64 + i * 16 + lr) * 32 + ko];
        if (pf) {
            #pragma unroll
            for (int j = 2; j < 4; ++j) {
                f16* dp = isA_[j] ? &As[ns][coff[j]] : &Bs[ns][coff[j]];
                __builtin_amdgcn_global_load_lds(
                    (const __attribute__((address_space(1))) unsigned int*)(gb[j] + kn),
                    (__attribute__((address_space(3))) unsigned int*)dp, 16, 0, 0);
            }
        }

        asm volatile("s_waitcnt lgkmcnt(4)" ::: "memory");
        __builtin_amdgcn_sched_barrier(0);
        __builtin_amdgcn_s_setprio(1);
        #pragma unroll
        for (int i = 0; i < 4; ++i)
            #pragma unroll
            for (int j = 0; j < 4; ++j)
                acc[i][j] = __builtin_amdgcn_mfma_f32_16x16x32_f16(af[i], bf[j], acc[i][j], 0, 0, 0);
        __builtin_amdgcn_s_setprio(0);

        asm volatile("s_waitcnt lgkmcnt(0)" ::: "memory");
        __builtin_amdgcn_sched_barrier(0);
        __builtin_amdgcn_s_setprio(1);
        #pragma unroll
        for (int i = 0; i < 4; ++i)
            #pragma unroll
            for (int j = 0; j < 4; ++j)
                acc[4 + i][j] = __builtin_amdgcn_mfma_f32_16x16x32_f16(ag[i], bf[j], acc[4 + i][j], 0, 0, 0);
        __builtin_amdgcn_s_setprio(0);

        if (pf) {
            asm volatile("s_waitcnt vmcnt(0)" ::: "memory");
            __builtin_amdgcn_sched_barrier(0);
            __builtin_amdgcn_s_barrier();
            asm volatile("" ::: "memory");
        }
    }

    float* Cp = C + (size_t)lz * plane;
    #pragma unroll
    for (int i = 0; i < 8; ++i) {
        int row = m0 + wm + i * 16 + (lane >> 4) * 4;
        #pragma unroll
        for (int j = 0; j < 4; ++j) {
            int col = n0 + wn + j * 16 + lr;
            #pragma unroll
            for (int rr = 0; rr < 4; ++rr)
                Cp[(size_t)(row + rr) * N + col] = acc[i][j][rr];
        }
    }
}

// ---------------------------------------------------------------------------
// Fallback fp32 GEMM (round-1 verified, used only if ws_size tiny)
// ---------------------------------------------------------------------------
__global__ __launch_bounds__(256) void kan_gemm(
    const float* __restrict__ X, const float* __restrict__ BW,
    const float* __restrict__ SW, float* __restrict__ Y, int KIN, int OUT)
{
    __shared__ __align__(16) float Asf[72][68];
    __shared__ __align__(16) float Bsf[72][68];
    const int tid = threadIdx.x;
    const int n0 = blockIdx.x * 64;
    const int m0 = blockIdx.y * 64;
    const int tx = tid & 15;
    const int ty = tid >> 4;
    float acc[4][4] = {};
    for (int k0 = 0; k0 < KIN; k0 += 8) {
        #pragma unroll
        for (int rep = 0; rep < 2; ++rep) {
            int idx = rep * 256 + tid;
            int r = idx >> 3, c = idx & 7;
            float x = X[(size_t)(m0 + r) * KIN + k0 + c];
            int bk = c * 9;
            Asf[bk][r] = x;
            #pragma unroll
            for (int z = 0; z < 8; ++z) Asf[bk + 1 + z][r] = 0.0f;
            float xs = (x + 2.2f) * 2.5f;
            float fj = floorf(xs);
            int j = (int)fj;
            if (j >= 0 && j <= 10) {
                float t = xs - fj;
                float t2 = t * t, t3 = t2 * t;
                float omt = 1.0f - t;
                float p0 = omt * omt * omt * (1.0f / 6.0f);
                float p1 = (3.0f * t3 - 6.0f * t2 + 4.0f) * (1.0f / 6.0f);
                float p2 = (-3.0f * t3 + 3.0f * t2 + 3.0f * t + 1.0f) * (1.0f / 6.0f);
                float p3 = t3 * (1.0f / 6.0f);
                if (j >= 3) Asf[bk + 1 + j - 3][r] = p0;
                if (j >= 2 && j <= 9) Asf[bk + 1 + j - 2][r] = p1;
                if (j >= 1 && j <= 8) Asf[bk + 1 + j - 1][r] = p2;
                if (j <= 7) Asf[bk + 1 + j][r] = p3;
            }
        }
        #pragma unroll
        for (int rep = 0; rep < 16; ++rep) {
            int idx = rep * 256 + tid;
            int ol = idx >> 6;
            int l = idx & 63;
            int i = l >> 3, cc = l & 7;
            float v = SW[((size_t)(n0 + ol) * KIN + k0 + i) * 8 + cc];
            Bsf[i * 9 + 1 + cc][ol] = rintf(v * 32.0f) * 0.03125f;
        }
        #pragma unroll
        for (int rep = 0; rep < 2; ++rep) {
            int idx = rep * 256 + tid;
            int ol = idx >> 3, cc = idx & 7;
            Bsf[cc * 9][ol] = BW[(size_t)(n0 + ol) * KIN + k0 + cc];
        }
        __syncthreads();
        #pragma unroll 8
        for (int kk = 0; kk < 72; ++kk) {
            float4 av = *(const float4*)&Asf[kk][ty * 4];
            float4 bv = *(const float4*)&Bsf[kk][tx * 4];
            acc[0][0] += av.x * bv.x; acc[0][1] += av.x * bv.y; acc[0][2] += av.x * bv.z; acc[0][3] += av.x * bv.w;
            acc[1][0] += av.y * bv.x; acc[1][1] += av.y * bv.y; acc[1][2] += av.y * bv.z; acc[1][3] += av.y * bv.w;
            acc[2][0] += av.z * bv.x; acc[2][1] += av.z * bv.y; acc[2][2] += av.z * bv.z; acc[2][3] += av.z * bv.w;
            acc[3][0] += av.w * bv.x; acc[3][1] += av.w * bv.y; acc[3][2] += av.w * bv.z; acc[3][3] += av.w * bv.w;
        }
        __syncthreads();
    }
    #pragma unroll
    for (int i = 0; i < 4; ++i) {
        float4 o = make_float4(acc[i][0], acc[i][1], acc[i][2], acc[i][3]);
        *(float4*)&Y[(size_t)(m0 + ty * 4 + i) * OUT + n0 + tx * 4] = o;
    }
}

// ---------------------------------------------------------------------------
// huxley_rd R13 (R6-verified): PAIRED rows, z = u1 + i*u2; 3 complex FFTs
// per TWO rows. See R6 ledger for exact-split derivation (gate real-even,
// phase conj-symmetric, bin-512 cos-only, sAbs via F1/F2 separation).
// ---------------------------------------------------------------------------
__device__ __forceinline__ float2 block_reduce_sum2(float2 v, float2* red, int tid) {
    red[tid] = v; __syncthreads();
    #pragma unroll
    for (int s = 128; s > 0; s >>= 1) {
        if (tid < s) {
            red[tid].x += red[tid + s].x;
            red[tid].y += red[tid + s].y;
        }
        __syncthreads();
    }
    float2 r = red[0]; __syncthreads();
    return r;
}
__device__ __forceinline__ float2 block_reduce_min2(float2 v, float2* red, int tid) {
    red[tid] = v; __syncthreads();
    #pragma unroll
    for (int s = 128; s > 0; s >>= 1) {
        if (tid < s) {
            red[tid].x = fminf(red[tid].x, red[tid + s].x);
            red[tid].y = fminf(red[tid].y, red[tid + s].y);
        }
        __syncthreads();
    }
    float2 r = red[0]; __syncthreads();
    return r;
}

__device__ void fft1024(float2* X, const float2* tw, int tid, bool inverse) {
    if (!inverse) {
        for (int sh = 9; sh >= 0; --sh) {
            int h = 1 << sh;
            #pragma unroll
            for (int q = 0; q < 2; ++q) {
                int b = tid + q * 256;
                int g = b >> sh, j = b & (h - 1);
                int i0 = (g << (sh + 1)) + j, i1 = i0 + h;
                float2 u = X[i0], v = X[i1];
                float dx = u.x - v.x, dy = u.y - v.y;
                X[i0] = make_float2(u.x + v.x, u.y + v.y);
                float2 w = tw[j << (9 - sh)];
                X[i1] = make_float2(dx * w.x + dy * w.y, dy * w.x - dx * w.y);
            }
            __syncthreads();
        }
    } else {
        for (int sh = 0; sh <= 9; ++sh) {
            int h = 1 << sh;
            #pragma unroll
            for (int q = 0; q < 2; ++q) {
                int b = tid + q * 256;
                int g = b >> sh, j = b & (h - 1);
                int i0 = (g << (sh + 1)) + j, i1 = i0 + h;
                float2 u = X[i0], v = X[i1];
                float2 w = tw[j << (9 - sh)];
                float tx2 = v.x * w.x - v.y * w.y;
                float ty2 = v.x * w.y + v.y * w.x;
                X[i0] = make_float2(u.x + tx2, u.y + ty2);
                X[i1] = make_float2(u.x - tx2, u.y - ty2);
            }
            __syncthreads();
        }
    }
}

__global__ __launch_bounds__(256) void huxley_kernel(
    const float* __restrict__ Pin, size_t plane, int S,
    float* __restrict__ dst,
    const float* __restrict__ sg, const float* __restrict__ dk,
    const float* __restrict__ pa, const float* __restrict__ pgam,
    const float* __restrict__ ptau, const float* __restrict__ pvel,
    const float* __restrict__ gp, const float* __restrict__ chi)
{
    __shared__ float2 A[1024];
    __shared__ float2 Bb[1024];
    __shared__ float2 sErg[1024];
    __shared__ float sAbs1[516];
    __shared__ float sAbs2[516];
    __shared__ float2 tw[512];
    __shared__ float2 red2[256];
    __shared__ float sG[516];

    const int tid = threadIdx.x;
    const int r0 = blockIdx.x * 2;
    const float* pin0 = Pin + (size_t)r0 * 1024;
    const float* pin1 = Pin + (size_t)(r0 + 1) * 1024;
    float* uo0 = dst + (size_t)r0 * 1024;
    float* uo1 = dst + (size_t)(r0 + 1) * 1024;

    for (int m = tid; m < 512; m += 256) {
        float s, c;
        sincosf(6.283185307179586f * (float)m * (1.0f / 1024.0f), &s, &c);
        tw[m] = make_float2(c, s);
    }
    for (int k = tid; k < 513; k += 256)
        sG[k] = 1.0f / (1.0f + expf(-sg[k]));
    for (int i = tid; i < 1024; i += 256) {
        float s0 = 0.0f, s1 = 0.0f;
        for (int ss = 0; ss < S; ++ss) {
            s0 += pin0[(size_t)ss * plane + i];
            s1 += pin1[(size_t)ss * plane + i];
        }
        A[i] = make_float2(s0, s1);   // packed: row1 + i*row2
    }
    __syncthreads();

    fft1024(A, tw, tid, false);       // A = Z (bit-reversed order)

    for (int p = tid; p < 1024; p += 256) {
        int k = (int)(__brev((unsigned)p) >> 22);
        int m = (k <= 512) ? k : 1024 - k;
        float g = sG[m] * (1.0f / 1024.0f);
        Bb[p] = make_float2(A[p].x * g, A[p].y * g);
    }
    __syncthreads();
    fft1024(Bb, tw, tid, true);
    for (int i = tid; i < 1024; i += 256) sErg[i] = Bb[i];
    __syncthreads();

    const float vv = pvel[0];
    for (int p = tid; p < 1024; p += 256) {
        int k = (int)(__brev((unsigned)p) >> 22);
        int m = (k <= 512) ? k : 1024 - k;
        float omg = 1.0f - sG[m];
        float2 z = A[p];
        float nx = z.x * omg, ny = z.y * omg;
        float ang = (k <= 512)
            ? (-6.283185307179586f * vv * (float)k * (1.0f / 1024.0f))
            : (6.283185307179586f * vv * (float)(1024 - k) * (1.0f / 1024.0f));
        float sn, cs;
        sincosf(ang, &sn, &cs);
        float yx, yy;
        if (k == 512) {
            yx = nx * cs;
            yy = ny * cs;
            sAbs1[512] = fabsf(nx * cs);
            sAbs2[512] = fabsf(ny * cs);
        } else {
            yx = nx * cs - ny * sn;
            yy = nx * sn + ny * cs;
            if (k < 512) {
                int p2 = (int)(__brev((unsigned)((1024 - k) & 1023)) >> 22);
                float2 z2 = A[p2];
                float f1x = 0.5f * (z.x + z2.x), f1y = 0.5f * (z.y - z2.y);
                float f2x = 0.5f * (z.y + z2.y), f2y = 0.5f * (z2.x - z.x);
                sAbs1[k] = omg * sqrtf(f1x * f1x + f1y * f1y);
                sAbs2[k] = omg * sqrtf(f2x * f2x + f2y * f2y);
            }
        }
        Bb[p] = make_float2(yx * (1.0f / 1024.0f), yy * (1.0f / 1024.0f));
    }
    __syncthreads();
    fft1024(Bb, tw, tid, true);

    float2 loc = make_float2(0.0f, 0.0f);
    for (int i = tid; i < 1024; i += 256) {
        loc.x += Bb[i].x * Bb[i].x;
        loc.y += Bb[i].y * Bb[i].y;
    }
    float2 trc = block_reduce_sum2(loc, red2, tid);

    loc = make_float2(0.0f, 0.0f);
    for (int k = tid; k < 513; k += 256) { loc.x += sAbs1[k]; loc.y += sAbs2[k]; }
    float2 msum = block_reduce_sum2(loc, red2, tid);
    float2 mean = make_float2(msum.x * (1.0f / 513.0f), msum.y * (1.0f / 513.0f));

    loc = make_float2(0.0f, 0.0f);
    for (int k = tid; k < 513; k += 256) {
        float d1 = sAbs1[k] - mean.x;
        float d2 = sAbs2[k] - mean.y;
        loc.x += d1 * d1; loc.y += d2 * d2;
    }
    float2 varsum = block_reduce_sum2(loc, red2, tid);

    loc = make_float2(3.4e38f, 3.4e38f);
    for (int k = tid; k < 513; k += 256) {
        loc.x = fminf(loc.x, sAbs1[k]);
        loc.y = fminf(loc.y, sAbs2[k]);
    }
    float2 lmin = block_reduce_min2(loc, red2, tid);

    const float tauv = ptau[0];
    float trcv[2]  = { trc.x, trc.y };
    float varv[2]  = { varsum.x, varsum.y };
    float lminv[2] = { lmin.x, lmin.y };
    float gpv[2]   = { gp[r0], gp[r0 + 1] };
    float chv[2]   = { chi[r0], chi[r0 + 1] };
    float cb[2];
    #pragma unroll
    for (int rr = 0; rr < 2; ++rr) {
        float det_pas = varv[rr] * (1.0f / 512.0f) + 1e-6f;
        float sd = sqrtf(det_pas);
        float denom = 2.0f * sd * sd * sd + 1e-8f;
        float c3 = (3.0f * gpv[rr] - trcv[rr] / tauv) / denom;
        c3 = fminf(fmaxf(c3, -0.999f), 0.999f);
        float ph = acosf(c3) * (1.0f / 3.0f);
        float amp = 2.0f * sqrtf(lminv[rr] * (1.0f / 3.0f) + 1e-8f);
        float nu = sqrtf(trcv[rr]);
        float achi = fabsf(chv[rr]);
        float cbest = 0.0f, ebest = -1.0f;
        #pragma unroll
        for (int kb = 0; kb < 3; ++kb) {
            float ck = amp * cosf(ph + 2.0943951023931953f * (float)kb) * expf(-achi * (float)kb);
            float ek = fabsf(ck) * nu;
            if (ek > ebest) { ebest = ek; cbest = ck; }
        }
        cb[rr] = cbest;
    }

    const float a = pa[0], gm = pgam[0];
    const float k0 = dk[0], k1 = dk[1], k2 = dk[2];
    for (int i = tid; i < 1024; i += 256) {
        float2 e = sErg[i];
        float2 l = (i > 0) ? sErg[i - 1] : make_float2(0.0f, 0.0f);
        float2 r = (i < 1023) ? sErg[i + 1] : make_float2(0.0f, 0.0f);
        float reac1 = e.x * (e.x - a) * (1.0f - e.x);
        float diff1 = k0 * l.x + k1 * e.x + k2 * r.x;
        float un1 = e.x + 0.1f * (reac1 + gm * diff1);
        float s1 = un1 + cb[0] * Bb[i].x;
        uo0[i] = s1 / (1.0f + expf(-s1));
        float reac2 = e.y * (e.y - a) * (1.0f - e.y);
        float diff2 = k0 * l.y + k1 * e.y + k2 * r.y;
        float un2 = e.y + 0.1f * (reac2 + gm * diff2);
        float s2 = un2 + cb[1] * Bb[i].y;
        uo1[i] = s2 / (1.0f + expf(-s2));
    }
}

// ---------------------------------------------------------------------------

extern "C" void kernel_launch(void* const* d_in, const int* in_sizes, int n_in,
                              void* d_out, int out_size, void* d_ws, size_t ws_size,
                              hipStream_t stream) {
    const float* c    = (const float*)d_in[0];
    const float* bw0  = (const float*)d_in[1];
    const float* sw0  = (const float*)d_in[2];
    const float* bw1  = (const float*)d_in[3];
    const float* sw1  = (const float*)d_in[4];
    const float* bw2  = (const float*)d_in[5];
    const float* sw2  = (const float*)d_in[6];
    const float* sg   = (const float*)d_in[7];
    const float* dk   = (const float*)d_in[8];
    const float* pa   = (const float*)d_in[9];
    const float* pgam = (const float*)d_in[10];
    const float* ptau = (const float*)d_in[11];
    const float* pvel = (const float*)d_in[12];
    const float* gp   = (const float*)d_in[13];
    const float* chi  = (const float*)d_in[14];

    const int B = 4096, NIN = 512, W = 1024, NOUT = 1024;
    const int KE0 = 19 * NIN, KE1 = 19 * W;
    const size_t MN = (size_t)B * W;
    const size_t BE = (size_t)W * KE1 * 2;      // Bexp bytes (39.85 MB)
    dim3 blk(256);
    dim3 gblk(512);

    // ---- pick (CH, S): {4096,8} -> gemm grid 4x16x8 = 512 = 2 blocks/CU
    //      (ring-2 kernel, 64KB LDS); else S<=4 -> ring-4 kernel (1/CU). ----
    struct Cand { int CH, S; };
    const Cand cands[] = {
        {4096, 8},
        {4096, 4}, {4096, 3}, {2048, 4}, {2048, 3}, {1024, 4},
        {512, 4}, {256, 4}
    };
    int CH = 0, S = 1;
    for (const auto& cd : cands) {
        size_t need = BE + (size_t)cd.CH * KE1 * 2 + (size_t)cd.S * MN * 4;
        if (need <= ws_size) { CH = cd.CH; S = cd.S; break; }
    }

    if (CH > 0) {
        f16* Bexp = (f16*)d_ws;
        float* P  = (float*)((char*)d_ws + BE);                // S planes of M x N fp32
        f16* Aexp = (f16*)((char*)d_ws + BE + (size_t)S * MN * 4);
        const bool deep = (S == 8);

        // ceil-split Kc (multiple of 32); kernel clamps last split
        const int Kc0 = ((KE0 / 32 + S - 1) / S) * 32;
        const int Kc1 = ((KE1 / 32 + S - 1) / S) * 32;

        // ---- layer 0: KIN=512 ----
        prep_b<<<(W * NIN) / 256, blk, 0, stream>>>(bw0, sw0, Bexp, NIN, 9);
        for (int r0 = 0; r0 < B; r0 += CH) {
            expand_sum_a<<<(CH * NIN) / 256, blk, 0, stream>>>(
                c + (size_t)r0 * NIN, 0, 1, Aexp, NIN, 9);
            if (deep)
                gemm_mfma2<<<dim3(W / 256, CH / 256, S), gblk, 0, stream>>>(
                    Aexp, Bexp, P + (size_t)r0 * W, KE0, Kc0, MN, W);
            else
                gemm_mfma<<<dim3(W / 256, CH / 256, S), gblk, 0, stream>>>(
                    Aexp, Bexp, P + (size_t)r0 * W, KE0, Kc0, MN, W);
        }
        // ---- layer 1: KIN=1024 ----
        prep_b<<<(W * W) / 256, blk, 0, stream>>>(bw1, sw1, Bexp, W, 10);
        for (int r0 = 0; r0 < B; r0 += CH) {
            expand_sum_a<<<(CH * W) / 256, blk, 0, stream>>>(
                P + (size_t)r0 * W, MN, S, Aexp, W, 10);
            if (deep)
                gemm_mfma2<<<dim3(W / 256, CH / 256, S), gblk, 0, stream>>>(
                    Aexp, Bexp, P + (size_t)r0 * W, KE1, Kc1, MN, W);
            else
                gemm_mfma<<<dim3(W / 256, CH / 256, S), gblk, 0, stream>>>(
                    Aexp, Bexp, P + (size_t)r0 * W, KE1, Kc1, MN, W);
        }
        // ---- layer 2 ----
        prep_b<<<(NOUT * W) / 256, blk, 0, stream>>>(bw2, sw2, Bexp, W, 10);
        for (int r0 = 0; r0 < B; r0 += CH) {
            expand_sum_a<<<(CH * W) / 256, blk, 0, stream>>>(
                P + (size_t)r0 * W, MN, S, Aexp, W, 10);
            if (deep)
                gemm_mfma2<<<dim3(NOUT / 256, CH / 256, S), gblk, 0, stream>>>(
                    Aexp, Bexp, P + (size_t)r0 * W, KE1, Kc1, MN, NOUT);
            else
                gemm_mfma<<<dim3(NOUT / 256, CH / 256, S), gblk, 0, stream>>>(
                    Aexp, Bexp, P + (size_t)r0 * W, KE1, Kc1, MN, NOUT);
        }
        huxley_kernel<<<B / 2, blk, 0, stream>>>(P, MN, S, (float*)d_out,
                                                 sg, dk, pa, pgam, ptau, pvel, gp, chi);
    } else {
        // fallback: round-1 fp32 path (needs only 33.6 MB ws)
        float* fx0 = (float*)d_ws;
        float* fx1 = fx0 + (size_t)B * W;
        dim3 g0(W / 64, B / 64);
        kan_gemm<<<g0, blk, 0, stream>>>(c,   bw0, sw0, fx0, NIN, W);
        kan_gemm<<<g0, blk, 0, stream>>>(fx0, bw1, sw1, fx1, W,   W);
        dim3 g2(NOUT / 64, B / 64);
        kan_gemm<<<g2, blk, 0, stream>>>(fx1, bw2, sw2, (float*)d_out, W, NOUT);
        huxley_kernel<<<B / 2, blk, 0, stream>>>((float*)d_out, 0, 1, (float*)d_out,
                                                 sg, dk, pa, pgam, ptau, pvel, gp, chi);
    }
}